// Round 9
// baseline (1345.617 us; speedup 1.0000x reference)
//
#include <hip/hip_runtime.h>

// GINE-GNN forward on MI355X. Round 9:
//  - sort split: hist stores rank[e] (atomic w/ return, coalesced store);
//    place kernel = off[dst]+rank (no atomic) writing src_s (4B) + full-line
//    64B ea_s row copy. reorder_ea kernel deleted.
//  - agg_sorted: __launch_bounds__(256,8) for higher occupancy (gather-latency
//    hiding); body unchanged (round-6 proven).

#define N_  100000
#define E_  1600000
#define G_  2000
#define SCAN_NB 196          // ceil(N / 512)
#define NBLK 1563            // ceil(N / 64)

__device__ __forceinline__ float leaky_(float z) { return z >= 0.f ? z : 0.01f * z; }

// ---------------------------------------------------------------------------
// Counting sort of edges by dst: hist(+rank) -> scanA/B/C -> place.
// ---------------------------------------------------------------------------
__global__ __launch_bounds__(256) void hist_rank_kernel(
    const int* __restrict__ dst, int* __restrict__ cnt, int* __restrict__ rank)
{
#pragma unroll 4
    for (int e = blockIdx.x * 256 + threadIdx.x; e < E_; e += gridDim.x * 256)
        rank[e] = atomicAdd(&cnt[dst[e]], 1);
}

__global__ __launch_bounds__(256) void scanA(
    const int* __restrict__ cnt, int* __restrict__ blocksum)
{
    __shared__ int s[256];
    const int t = threadIdx.x, b = blockIdx.x;
    const int i0 = (b * 256 + t) * 2;
    int v = 0;
    if (i0 < N_) v += cnt[i0];
    if (i0 + 1 < N_) v += cnt[i0 + 1];
    s[t] = v; __syncthreads();
    for (int o = 128; o > 0; o >>= 1) { if (t < o) s[t] += s[t + o]; __syncthreads(); }
    if (t == 0) blocksum[b] = s[0];
}

__global__ __launch_bounds__(256) void scanB(
    const int* __restrict__ blocksum, int* __restrict__ blockpref)
{
    __shared__ int s[256];
    const int t = threadIdx.x;
    int v = (t < SCAN_NB) ? blocksum[t] : 0;
    s[t] = v; __syncthreads();
    for (int o = 1; o < 256; o <<= 1) {
        int u = (t >= o) ? s[t - o] : 0;
        __syncthreads(); s[t] += u; __syncthreads();
    }
    blockpref[t] = s[t] - v;   // exclusive
}

__global__ __launch_bounds__(256) void scanC(
    const int* __restrict__ cnt, int* __restrict__ off,
    const int* __restrict__ blockpref)
{
    __shared__ int s[256];
    const int t = threadIdx.x, b = blockIdx.x;
    const int i0 = (b * 256 + t) * 2;
    int v0 = (i0 < N_) ? cnt[i0] : 0;
    int v1 = (i0 + 1 < N_) ? cnt[i0 + 1] : 0;
    int pv = v0 + v1;
    s[t] = pv; __syncthreads();
    for (int o = 1; o < 256; o <<= 1) {
        int u = (t >= o) ? s[t - o] : 0;
        __syncthreads(); s[t] += u; __syncthreads();
    }
    int run = blockpref[b] + s[t] - pv;
    if (i0 < N_) {
        off[i0] = run; run += v0;
        if (i0 + 1 < N_) off[i0 + 1] = run;
    }
    if (b == 0 && t == 0) off[N_] = E_;
}

// place: p = off[dst]+rank (no atomic). src_s[p] 4B; ea_s[p] = full 64B line.
__global__ __launch_bounds__(256) void place_kernel(
    const int* __restrict__ src, const int* __restrict__ dst,
    const int* __restrict__ rank, const int* __restrict__ off,
    const float* __restrict__ edge_attr,
    int* __restrict__ src_s, float* __restrict__ ea_s)
{
#pragma unroll 2
    for (int e = blockIdx.x * 256 + threadIdx.x; e < E_; e += gridDim.x * 256) {
        const int p = off[dst[e]] + rank[e];
        src_s[p] = src[e];
        const float4* __restrict__ ea = (const float4*)(edge_attr + (size_t)e * 16);
        float4* __restrict__ eo = (float4*)(ea_s + (size_t)p * 16);
        float4 a0 = ea[0], a1 = ea[1], a2 = ea[2], a3 = ea[3];
        eo[0] = a0; eo[1] = a1; eo[2] = a2; eo[3] = a3;
    }
}

// ---------------------------------------------------------------------------
// Sorted-edge aggregation (round-6 proven body): one wave owns DPW consecutive
// destinations; 32-edge LDS chunks (double-buffered, coalesced staging),
// all 32 x[src] gathers issued before compute, ea rows via broadcast ds_read.
// ---------------------------------------------------------------------------
#define DPW 13
#define CHUNK 32

template<int CI>
__global__ __launch_bounds__(256, 8) void agg_sorted(
    const float* __restrict__ ea_s,      // [E,16] sorted by dst
    const int* __restrict__ src_s,       // [E] sorted by dst
    const int* __restrict__ off,
    const float* __restrict__ We, const float* __restrict__ be,
    const float* __restrict__ x, float* __restrict__ agg)
{
    __shared__ __align__(16) float s_ea[4][2][CHUNK * 16];   // 16 KB
    __shared__ int s_src[4][2][CHUNK];                       // 1 KB
    const int t = threadIdx.x;
    const int lane = t & 63;
    const int w = t >> 6;
    const int wid = __builtin_amdgcn_readfirstlane(blockIdx.x * 4 + w);

    float wcol[16];
#pragma unroll
    for (int k = 0; k < 16; ++k) wcol[k] = 0.f;
    float beL = 0.f;
    if (lane < CI) {
#pragma unroll
        for (int k = 0; k < 16; ++k) wcol[k] = We[k * CI + lane];
        beL = be[lane];
    }
    const int ln = (lane < CI) ? lane : 0;

    const int d0 = wid * DPW;
    if (d0 >= N_) return;
    const int d1 = min(d0 + DPW, N_);
    const int pw0 = off[d0];
    const int pw1 = off[d1];

    int d = d0;
    int e1 = off[d0 + 1];
    float acc = 0.f;
    int buf = 0;

    // stage chunk 0
    {
        const int m = min(CHUNK, pw1 - pw0);
#pragma unroll
        for (int j = 0; j < 2; ++j) {
            const int f = lane + 64 * j;
            float4 v = make_float4(0.f, 0.f, 0.f, 0.f);
            if (f < m * 4) v = *(const float4*)&ea_s[(size_t)pw0 * 16 + f * 4];
            *(float4*)&s_ea[w][0][f * 4] = v;
        }
        if (lane < CHUNK)
            s_src[w][0][lane] = (lane < m) ? src_s[pw0 + lane] : 0;
    }
    __builtin_amdgcn_wave_barrier();

    for (int cp = pw0; cp < pw1; cp += CHUNK) {
        const int m = min(CHUNK, pw1 - cp);
        const int np = cp + CHUNK;
        const int nm = min(CHUNK, pw1 - np);   // may be <= 0

        // prefetch next chunk into registers (consumed after compute)
        float4 pre0 = make_float4(0.f, 0.f, 0.f, 0.f), pre1 = pre0;
        int psrc = 0;
        if (nm > 0) {
            { int f = lane;      if (f < nm * 4) pre0 = *(const float4*)&ea_s[(size_t)np * 16 + f * 4]; }
            { int f = lane + 64; if (f < nm * 4) pre1 = *(const float4*)&ea_s[(size_t)np * 16 + f * 4]; }
            if (lane < nm) psrc = src_s[np + lane];
        }

        // issue all gathers for the current chunk (OOB entries gather x[0])
        float xr[CHUNK];
#pragma unroll
        for (int i = 0; i < CHUNK; ++i) {
            const int s = s_src[w][buf][i];           // broadcast ds_read
            xr[i] = x[(size_t)s * CI + ln];
        }

        // compute: dot(ea_row, wcol) per edge, uniform dest-boundary flush
#pragma unroll
        for (int i = 0; i < CHUNK; ++i) {
            if (i >= m) break;
            while (cp + i == e1) {
                if (lane < CI) agg[(size_t)d * CI + lane] = acc;
                acc = 0.f; ++d;
                e1 = off[d + 1];
            }
            const float* er = &s_ea[w][buf][i * 16];
            float dotv = beL;
#pragma unroll
            for (int k = 0; k < 16; k += 4) {
                float4 ev = *(const float4*)&er[k];    // broadcast ds_read_b128
                dotv += ev.x * wcol[k] + ev.y * wcol[k + 1]
                      + ev.z * wcol[k + 2] + ev.w * wcol[k + 3];
            }
            float mm = xr[i] + dotv;
            acc += (mm > 0.f ? mm : 0.f);
        }

        // commit prefetch to the alternate buffer
        if (nm > 0) {
            *(float4*)&s_ea[w][buf ^ 1][lane * 4] = pre0;
            *(float4*)&s_ea[w][buf ^ 1][(lane + 64) * 4] = pre1;
            if (lane < CHUNK) s_src[w][buf ^ 1][lane] = psrc;
        }
        __builtin_amdgcn_wave_barrier();
        buf ^= 1;
    }

    // flush current dest + trailing zero-degree dests
    while (d < d1) {
        if (lane < CI) agg[(size_t)d * CI + lane] = acc;
        acc = 0.f; ++d;
    }
}

// ---------------------------------------------------------------------------
// Node GEMM (round 4/5): per-block partial BN stats, float4 staging.
// ---------------------------------------------------------------------------
template<int CI, int MODE>
__global__ __launch_bounds__(256, 4) void node_gemm(
    const float* __restrict__ in,
    const float* __restrict__ agg,   // MODE 0
    const float* __restrict__ eps,   // MODE 0
    const float* __restrict__ g1,    // MODE 1
    const float* __restrict__ bt1,   // MODE 1
    const float* __restrict__ stIn,  // MODE 1
    const float* __restrict__ W, const float* __restrict__ bias_,
    float* __restrict__ outbuf, float* __restrict__ partial)
{
    __shared__ __align__(16) float a_lds[64][CI + 4];
    __shared__ __align__(16) float w_lds[CI][68];
    __shared__ float s_sc[64], s_sh[64];
    const int t = threadIdx.x;
    const int n0 = blockIdx.x * 64;
    constexpr int QR = CI / 4;

    if (MODE == 1) {
        if (t < 64) {
            float mean = stIn[t] * (1.0f / N_);
            float var  = stIn[64 + t] * (1.0f / N_) - mean * mean;
            float sc = g1[t] * rsqrtf(var + 1e-5f);
            s_sc[t] = sc;
            s_sh[t] = bt1[t] - mean * sc;
        }
        __syncthreads();
    }

    if (MODE == 0) {
        const float hs = 1.0f + eps[0];
        for (int f = t; f < 64 * QR; f += 256) {
            int i = f / QR, q = f - i * QR;
            int n = n0 + i;
            float4 val = make_float4(0.f, 0.f, 0.f, 0.f);
            if (n < N_) {
                float4 xa = *(const float4*)&in[(size_t)n * CI + q * 4];
                float4 ag = *(const float4*)&agg[(size_t)n * CI + q * 4];
                val = make_float4(hs * xa.x + ag.x, hs * xa.y + ag.y,
                                  hs * xa.z + ag.z, hs * xa.w + ag.w);
            }
            *(float4*)&a_lds[i][q * 4] = val;
        }
    } else {
        for (int f = t; f < 64 * QR; f += 256) {
            int i = f / QR, q = f - i * QR;
            int n = n0 + i;
            float4 val = make_float4(0.f, 0.f, 0.f, 0.f);
            if (n < N_) {
                float4 uv = *(const float4*)&in[(size_t)n * CI + q * 4];
                int c = q * 4;
                val = make_float4(leaky_(uv.x * s_sc[c]     + s_sh[c]),
                                  leaky_(uv.y * s_sc[c + 1] + s_sh[c + 1]),
                                  leaky_(uv.z * s_sc[c + 2] + s_sh[c + 2]),
                                  leaky_(uv.w * s_sc[c + 3] + s_sh[c + 3]));
            }
            *(float4*)&a_lds[i][q * 4] = val;
        }
    }
    for (int f = t; f < CI * 16; f += 256) {
        int k = f >> 4, cq = f & 15;
        *(float4*)&w_lds[k][cq * 4] = *(const float4*)&W[k * 64 + cq * 4];
    }
    __syncthreads();

    const int tr = t & 15;
    const int c0 = (t >> 4) * 4;
    float acc[4][4] = {};
#pragma unroll 2
    for (int k = 0; k < CI; k += 4) {
        float ar[4][4];
#pragma unroll
        for (int j = 0; j < 4; ++j)
            *(float4*)&ar[j][0] = *(const float4*)&a_lds[tr + 16 * j][k];
#pragma unroll
        for (int kk = 0; kk < 4; ++kk) {
            float4 b = *(const float4*)&w_lds[k + kk][c0];
#pragma unroll
            for (int j = 0; j < 4; ++j) {
                acc[j][0] += ar[j][kk] * b.x;
                acc[j][1] += ar[j][kk] * b.y;
                acc[j][2] += ar[j][kk] * b.z;
                acc[j][3] += ar[j][kk] * b.w;
            }
        }
    }

    const float4 bb = *(const float4*)&bias_[c0];
    const float bias[4] = { bb.x, bb.y, bb.z, bb.w };
    float ls[4] = {}, lq[4] = {};
#pragma unroll
    for (int j = 0; j < 4; ++j) {
        int n = n0 + tr + 16 * j;
        if (n < N_) {
            float o[4];
#pragma unroll
            for (int cc = 0; cc < 4; ++cc) {
                o[cc] = acc[j][cc] + bias[cc];
                ls[cc] += o[cc];
                lq[cc] += o[cc] * o[cc];
            }
            *(float4*)&outbuf[(size_t)n * 64 + c0] = make_float4(o[0], o[1], o[2], o[3]);
        }
    }
#pragma unroll
    for (int m = 1; m <= 8; m <<= 1) {
#pragma unroll
        for (int cc = 0; cc < 4; ++cc) {
            ls[cc] += __shfl_xor(ls[cc], m);
            lq[cc] += __shfl_xor(lq[cc], m);
        }
    }
    if (tr == 0) {
#pragma unroll
        for (int cc = 0; cc < 4; ++cc) {
            partial[(size_t)(c0 + cc) * NBLK + blockIdx.x]      = ls[cc];
            partial[(size_t)(64 + c0 + cc) * NBLK + blockIdx.x] = lq[cc];
        }
    }
}

__global__ __launch_bounds__(256) void finalize_stats(
    const float* __restrict__ partial, float* __restrict__ stats)
{
    const int c = blockIdx.x;
    const int t = threadIdx.x;
    float s = 0.f;
    for (int b = t; b < NBLK; b += 256) s += partial[(size_t)c * NBLK + b];
    __shared__ float red[256];
    red[t] = s; __syncthreads();
    for (int o = 128; o > 0; o >>= 1) { if (t < o) red[t] += red[t + o]; __syncthreads(); }
    if (t == 0) stats[c] = red[0];
}

// ---------------------------------------------------------------------------
__global__ __launch_bounds__(256) void apply_bn_leaky(
    const float* __restrict__ v, const float* __restrict__ st,
    const float* __restrict__ g, const float* __restrict__ b,
    float* __restrict__ xout)
{
    size_t idx = ((size_t)blockIdx.x * 256 + threadIdx.x) * 4;
    if (idx >= (size_t)N_ * 64) return;
    int c0 = (int)(idx & 63);
    float4 vv = *(const float4*)&v[idx];
    float vi[4] = { vv.x, vv.y, vv.z, vv.w };
    float o[4];
#pragma unroll
    for (int cc = 0; cc < 4; ++cc) {
        int c = c0 + cc;
        float mean = st[c] * (1.0f / N_);
        float var  = st[64 + c] * (1.0f / N_) - mean * mean;
        float sc = g[c] * rsqrtf(var + 1e-5f);
        float sh = b[c] - mean * sc;
        o[cc] = leaky_(vi[cc] * sc + sh);
    }
    *(float4*)&xout[idx] = make_float4(o[0], o[1], o[2], o[3]);
}

// ---------------------------------------------------------------------------
__global__ __launch_bounds__(256) void pool_kernel(
    const float* __restrict__ x, float* __restrict__ pool)
{
    const int c = threadIdx.x & 63;
    const int g = blockIdx.x * 4 + (threadIdx.x >> 6);
    const float* p = x + (size_t)g * 50 * 64 + c;
    float s = 0.f;
#pragma unroll
    for (int j = 0; j < 50; ++j) s += p[(size_t)j * 64];
    pool[(size_t)g * 64 + c] = s;
}

// g0[g][c] = pool[g] @ W0b + b0  (W0b = W0 rows 64..127). 2 graphs/block.
__global__ __launch_bounds__(256) void pool_mlp0(
    const float* __restrict__ pool, const float* __restrict__ W0,
    const float* __restrict__ b0, float* __restrict__ g0)
{
    const int t = threadIdx.x;
    const int g = blockIdx.x * 2 + (t >> 7);
    const int c = t & 127;
    float s = b0[c];
    const float* pr = pool + (size_t)g * 64;
#pragma unroll 4
    for (int k = 0; k < 64; ++k)
        s += pr[k] * W0[(size_t)(64 + k) * 128 + c];
    g0[(size_t)g * 128 + c] = s;
}

// ---------------------------------------------------------------------------
// Fused MLP head: h1 = leaky(x@W0a + g0[n/50]); h2 = leaky(h1@W1 + b1);
// out = h2@Wf + bf.  128 nodes/block, 256 threads, 8x8 micro-tile.
// ---------------------------------------------------------------------------
__global__ __launch_bounds__(256, 2) void mlp_kernel(
    const float* __restrict__ x, const float* __restrict__ g0,
    const float* __restrict__ W0,
    const float* __restrict__ W1, const float* __restrict__ b1,
    const float* __restrict__ Wf, const float* __restrict__ bf,
    float* __restrict__ out)
{
    __shared__ __align__(16) float a_lds[128][132];   // 67.6 KB
    __shared__ __align__(16) float w_lds[16][132];    // 8.4 KB
    __shared__ __align__(16) float sWfT[2][128];
    __shared__ int sbid[128];
    const int t = threadIdx.x;
    const int n0 = blockIdx.x * 128;

    for (int f = t; f < 128 * 16; f += 256) {
        int i = f >> 4, q = f & 15;
        int n = n0 + i;
        float4 val = make_float4(0.f, 0.f, 0.f, 0.f);
        if (n < N_) val = *(const float4*)&x[(size_t)n * 64 + q * 4];
        *(float4*)&a_lds[i][q * 4] = val;
    }
    if (t < 128) {
        int n = n0 + t;
        sbid[t] = (n < N_) ? (n / 50) : (G_ - 1);
        sWfT[0][t] = Wf[t * 2];
        sWfT[1][t] = Wf[t * 2 + 1];
    }

    const int tr = t & 15;
    const int c0 = (t >> 4) * 8;
    float acc[8][8];

#pragma unroll
    for (int j = 0; j < 8; ++j)
#pragma unroll
        for (int cc = 0; cc < 8; ++cc) acc[j][cc] = 0.f;

    for (int kc = 0; kc < 64; kc += 16) {
        __syncthreads();
        for (int f = t; f < 16 * 32; f += 256) {
            int k = f >> 5, cq = f & 31;
            *(float4*)&w_lds[k][cq * 4] = *(const float4*)&W0[(size_t)(kc + k) * 128 + cq * 4];
        }
        __syncthreads();
        for (int k = 0; k < 16; k += 4) {
            float ar[8][4];
#pragma unroll
            for (int j = 0; j < 8; ++j)
                *(float4*)&ar[j][0] = *(const float4*)&a_lds[tr + 16 * j][kc + k];
#pragma unroll
            for (int kk = 0; kk < 4; ++kk) {
                float4 bA = *(const float4*)&w_lds[k + kk][c0];
                float4 bB = *(const float4*)&w_lds[k + kk][c0 + 4];
#pragma unroll
                for (int j = 0; j < 8; ++j) {
                    acc[j][0] += ar[j][kk] * bA.x;
                    acc[j][1] += ar[j][kk] * bA.y;
                    acc[j][2] += ar[j][kk] * bA.z;
                    acc[j][3] += ar[j][kk] * bA.w;
                    acc[j][4] += ar[j][kk] * bB.x;
                    acc[j][5] += ar[j][kk] * bB.y;
                    acc[j][6] += ar[j][kk] * bB.z;
                    acc[j][7] += ar[j][kk] * bB.w;
                }
            }
        }
    }
    __syncthreads();
#pragma unroll
    for (int j = 0; j < 8; ++j) {
        int row = tr + 16 * j;
        const float* gr = g0 + (size_t)sbid[row] * 128;
        float4 gA = *(const float4*)&gr[c0];
        float4 gB = *(const float4*)&gr[c0 + 4];
        float o[8] = { acc[j][0] + gA.x, acc[j][1] + gA.y, acc[j][2] + gA.z, acc[j][3] + gA.w,
                       acc[j][4] + gB.x, acc[j][5] + gB.y, acc[j][6] + gB.z, acc[j][7] + gB.w };
#pragma unroll
        for (int cc = 0; cc < 8; ++cc) o[cc] = leaky_(o[cc]);
        *(float4*)&a_lds[row][c0]     = make_float4(o[0], o[1], o[2], o[3]);
        *(float4*)&a_lds[row][c0 + 4] = make_float4(o[4], o[5], o[6], o[7]);
    }

#pragma unroll
    for (int j = 0; j < 8; ++j)
#pragma unroll
        for (int cc = 0; cc < 8; ++cc) acc[j][cc] = 0.f;

    for (int kc = 0; kc < 128; kc += 16) {
        __syncthreads();
        for (int f = t; f < 16 * 32; f += 256) {
            int k = f >> 5, cq = f & 31;
            *(float4*)&w_lds[k][cq * 4] = *(const float4*)&W1[(size_t)(kc + k) * 128 + cq * 4];
        }
        __syncthreads();
        for (int k = 0; k < 16; k += 4) {
            float ar[8][4];
#pragma unroll
            for (int j = 0; j < 8; ++j)
                *(float4*)&ar[j][0] = *(const float4*)&a_lds[tr + 16 * j][kc + k];
#pragma unroll
            for (int kk = 0; kk < 4; ++kk) {
                float4 bA = *(const float4*)&w_lds[k + kk][c0];
                float4 bB = *(const float4*)&w_lds[k + kk][c0 + 4];
#pragma unroll
                for (int j = 0; j < 8; ++j) {
                    acc[j][0] += ar[j][kk] * bA.x;
                    acc[j][1] += ar[j][kk] * bA.y;
                    acc[j][2] += ar[j][kk] * bA.z;
                    acc[j][3] += ar[j][kk] * bA.w;
                    acc[j][4] += ar[j][kk] * bB.x;
                    acc[j][5] += ar[j][kk] * bB.y;
                    acc[j][6] += ar[j][kk] * bB.z;
                    acc[j][7] += ar[j][kk] * bB.w;
                }
            }
        }
    }
    __syncthreads();
    {
        float4 bb0 = *(const float4*)&b1[c0];
        float4 bb1 = *(const float4*)&b1[c0 + 4];
        float bias[8] = { bb0.x, bb0.y, bb0.z, bb0.w, bb1.x, bb1.y, bb1.z, bb1.w };
#pragma unroll
        for (int j = 0; j < 8; ++j) {
            int row = tr + 16 * j;
            float o[8];
#pragma unroll
            for (int cc = 0; cc < 8; ++cc) o[cc] = leaky_(acc[j][cc] + bias[cc]);
            *(float4*)&a_lds[row][c0]     = make_float4(o[0], o[1], o[2], o[3]);
            *(float4*)&a_lds[row][c0 + 4] = make_float4(o[4], o[5], o[6], o[7]);
        }
    }
    __syncthreads();

    {
        int i = t >> 1, c = t & 1;
        int n = n0 + i;
        if (n < N_) {
            float s = bf[c];
            for (int k = 0; k < 128; k += 4) {
                float4 av = *(const float4*)&a_lds[i][k];
                float4 wv = *(const float4*)&sWfT[c][k];
                s += av.x * wv.x + av.y * wv.y + av.z * wv.z + av.w * wv.w;
            }
            out[(size_t)n * 2 + c] = s;
        }
    }
}

// ---------------------------------------------------------------------------
extern "C" void kernel_launch(void* const* d_in, const int* in_sizes, int n_in,
                              void* d_out, int out_size, void* d_ws, size_t ws_size,
                              hipStream_t stream)
{
    (void)in_sizes; (void)n_in; (void)out_size; (void)ws_size;

    const float* x0    = (const float*)d_in[0];
    const int*   eidx  = (const int*)d_in[1];
    const float* eattr = (const float*)d_in[2];
    const float* L[3][11];
    for (int l = 0; l < 3; ++l)
        for (int j = 0; j < 11; ++j)
            L[l][j] = (const float*)d_in[4 + l * 11 + j];
    const float* mlp0W = (const float*)d_in[37];
    const float* mlp0b = (const float*)d_in[38];
    const float* mlp1W = (const float*)d_in[39];
    const float* mlp1b = (const float*)d_in[40];
    const float* finW  = (const float*)d_in[41];
    const float* finb  = (const float*)d_in[42];
    float* out = (float*)d_out;

    float* ws    = (float*)d_ws;
    float* agg   = ws;                          // N*64 (reused as v after gemm1)
    float* u     = agg  + (size_t)N_ * 64;      // N*64
    float* xbuf  = u    + (size_t)N_ * 64;      // N*64
    float* pool  = xbuf + (size_t)N_ * 64;      // G*64
    float* g0    = pool + (size_t)G_ * 64;      // G*128
    float* stats = g0   + (size_t)G_ * 128;     // 768
    float* partial = stats + 768;               // 128*NBLK
    int*   off   = (int*)(partial + 128 * NBLK); // N+1 (+1 pad)
    int*   cnt   = off + (N_ + 2);              // N
    int*   bsum  = cnt + N_;                    // 256
    int*   bpref = bsum + 256;                  // 256
    int*   rank  = bpref + 256;                 // E
    int*   src_s = rank + E_;                   // E
    float* ea_s  = (float*)((((uintptr_t)(src_s + E_)) + 63) & ~(uintptr_t)63); // E*16, 64B aligned
    float* v = agg;

    const int* src = eidx;
    const int* dst = eidx + E_;
    const int GB = NBLK;

    // ---- counting sort of edges by dst (rank-based, atomic-free placement) ----
    hipMemsetAsync(cnt, 0, (size_t)N_ * sizeof(int), stream);
    hist_rank_kernel<<<2048, 256, 0, stream>>>(dst, cnt, rank);
    scanA<<<SCAN_NB, 256, 0, stream>>>(cnt, bsum);
    scanB<<<1, 256, 0, stream>>>(bsum, bpref);
    scanC<<<SCAN_NB, 256, 0, stream>>>(cnt, off, bpref);
    place_kernel<<<2048, 256, 0, stream>>>(src, dst, rank, off, eattr, src_s, ea_s);

    const int AGGB = ((N_ + DPW - 1) / DPW + 3) / 4 + 1;

    for (int l = 0; l < 3; ++l) {
        float* s1 = stats + (2 * l) * 128;
        float* s2 = stats + (2 * l + 1) * 128;
        if (l == 0) {
            agg_sorted<40><<<AGGB, 256, 0, stream>>>(ea_s, src_s, off, L[0][1], L[0][2], x0, agg);
            node_gemm<40, 0><<<GB, 256, 0, stream>>>(x0, agg, L[0][0], nullptr, nullptr, nullptr,
                                                     L[0][3], L[0][4], u, partial);
        } else {
            agg_sorted<64><<<AGGB, 256, 0, stream>>>(ea_s, src_s, off, L[l][1], L[l][2], xbuf, agg);
            node_gemm<64, 0><<<GB, 256, 0, stream>>>(xbuf, agg, L[l][0], nullptr, nullptr, nullptr,
                                                     L[l][3], L[l][4], u, partial);
        }
        finalize_stats<<<128, 256, 0, stream>>>(partial, s1);
        node_gemm<64, 1><<<GB, 256, 0, stream>>>(u, nullptr, nullptr, L[l][5], L[l][6], s1,
                                                 L[l][7], L[l][8], v, partial);
        finalize_stats<<<128, 256, 0, stream>>>(partial, s2);
        apply_bn_leaky<<<6250, 256, 0, stream>>>(v, s2, L[l][9], L[l][10], xbuf);
    }

    // ---- pool + per-graph mlp0 term + fused MLP head ----
    pool_kernel<<<G_ / 4, 256, 0, stream>>>(xbuf, pool);
    pool_mlp0<<<G_ / 2, 256, 0, stream>>>(pool, mlp0W, mlp0b, g0);
    mlp_kernel<<<(N_ + 127) / 128, 256, 0, stream>>>(xbuf, g0, mlp0W,
                                                     mlp1W, mlp1b, finW, finb, out);
}

// Round 10
// 1018.990 us; speedup vs baseline: 1.3205x; 1.3205x over previous
//
#include <hip/hip_runtime.h>

// GINE-GNN forward on MI355X. Round 10:
//  - REVERT agg_sorted to __launch_bounds__(256,4): the (256,8) cap gave a
//    64-VGPR budget -> xr[32] spilled to scratch (905MB HBM/dispatch, 235us).
//    52 VGPRs is this kernel's floor; occupancy 33% w/o spills beats 72% with.
//  - Keep round-9 rank/place sort (scatter+reorder_ea replaced; ~70us saved).

#define N_  100000
#define E_  1600000
#define G_  2000
#define SCAN_NB 196          // ceil(N / 512)
#define NBLK 1563            // ceil(N / 64)

__device__ __forceinline__ float leaky_(float z) { return z >= 0.f ? z : 0.01f * z; }

// ---------------------------------------------------------------------------
// Counting sort of edges by dst: hist(+rank) -> scanA/B/C -> place.
// ---------------------------------------------------------------------------
__global__ __launch_bounds__(256) void hist_rank_kernel(
    const int* __restrict__ dst, int* __restrict__ cnt, int* __restrict__ rank)
{
#pragma unroll 4
    for (int e = blockIdx.x * 256 + threadIdx.x; e < E_; e += gridDim.x * 256)
        rank[e] = atomicAdd(&cnt[dst[e]], 1);
}

__global__ __launch_bounds__(256) void scanA(
    const int* __restrict__ cnt, int* __restrict__ blocksum)
{
    __shared__ int s[256];
    const int t = threadIdx.x, b = blockIdx.x;
    const int i0 = (b * 256 + t) * 2;
    int v = 0;
    if (i0 < N_) v += cnt[i0];
    if (i0 + 1 < N_) v += cnt[i0 + 1];
    s[t] = v; __syncthreads();
    for (int o = 128; o > 0; o >>= 1) { if (t < o) s[t] += s[t + o]; __syncthreads(); }
    if (t == 0) blocksum[b] = s[0];
}

__global__ __launch_bounds__(256) void scanB(
    const int* __restrict__ blocksum, int* __restrict__ blockpref)
{
    __shared__ int s[256];
    const int t = threadIdx.x;
    int v = (t < SCAN_NB) ? blocksum[t] : 0;
    s[t] = v; __syncthreads();
    for (int o = 1; o < 256; o <<= 1) {
        int u = (t >= o) ? s[t - o] : 0;
        __syncthreads(); s[t] += u; __syncthreads();
    }
    blockpref[t] = s[t] - v;   // exclusive
}

__global__ __launch_bounds__(256) void scanC(
    const int* __restrict__ cnt, int* __restrict__ off,
    const int* __restrict__ blockpref)
{
    __shared__ int s[256];
    const int t = threadIdx.x, b = blockIdx.x;
    const int i0 = (b * 256 + t) * 2;
    int v0 = (i0 < N_) ? cnt[i0] : 0;
    int v1 = (i0 + 1 < N_) ? cnt[i0 + 1] : 0;
    int pv = v0 + v1;
    s[t] = pv; __syncthreads();
    for (int o = 1; o < 256; o <<= 1) {
        int u = (t >= o) ? s[t - o] : 0;
        __syncthreads(); s[t] += u; __syncthreads();
    }
    int run = blockpref[b] + s[t] - pv;
    if (i0 < N_) {
        off[i0] = run; run += v0;
        if (i0 + 1 < N_) off[i0 + 1] = run;
    }
    if (b == 0 && t == 0) off[N_] = E_;
}

// place: p = off[dst]+rank (no atomic). src_s[p] 4B; ea_s[p] = full 64B line.
__global__ __launch_bounds__(256) void place_kernel(
    const int* __restrict__ src, const int* __restrict__ dst,
    const int* __restrict__ rank, const int* __restrict__ off,
    const float* __restrict__ edge_attr,
    int* __restrict__ src_s, float* __restrict__ ea_s)
{
#pragma unroll 2
    for (int e = blockIdx.x * 256 + threadIdx.x; e < E_; e += gridDim.x * 256) {
        const int p = off[dst[e]] + rank[e];
        src_s[p] = src[e];
        const float4* __restrict__ ea = (const float4*)(edge_attr + (size_t)e * 16);
        float4* __restrict__ eo = (float4*)(ea_s + (size_t)p * 16);
        float4 a0 = ea[0], a1 = ea[1], a2 = ea[2], a3 = ea[3];
        eo[0] = a0; eo[1] = a1; eo[2] = a2; eo[3] = a3;
    }
}

// ---------------------------------------------------------------------------
// Sorted-edge aggregation (round-6 proven body, (256,4) = 52 VGPR no-spill):
// one wave owns DPW consecutive destinations; 32-edge LDS chunks
// (double-buffered, coalesced staging), all 32 x[src] gathers issued before
// compute, ea rows via broadcast ds_read.
// ---------------------------------------------------------------------------
#define DPW 13
#define CHUNK 32

template<int CI>
__global__ __launch_bounds__(256, 4) void agg_sorted(
    const float* __restrict__ ea_s,      // [E,16] sorted by dst
    const int* __restrict__ src_s,       // [E] sorted by dst
    const int* __restrict__ off,
    const float* __restrict__ We, const float* __restrict__ be,
    const float* __restrict__ x, float* __restrict__ agg)
{
    __shared__ __align__(16) float s_ea[4][2][CHUNK * 16];   // 16 KB
    __shared__ int s_src[4][2][CHUNK];                       // 1 KB
    const int t = threadIdx.x;
    const int lane = t & 63;
    const int w = t >> 6;
    const int wid = __builtin_amdgcn_readfirstlane(blockIdx.x * 4 + w);

    float wcol[16];
#pragma unroll
    for (int k = 0; k < 16; ++k) wcol[k] = 0.f;
    float beL = 0.f;
    if (lane < CI) {
#pragma unroll
        for (int k = 0; k < 16; ++k) wcol[k] = We[k * CI + lane];
        beL = be[lane];
    }
    const int ln = (lane < CI) ? lane : 0;

    const int d0 = wid * DPW;
    if (d0 >= N_) return;
    const int d1 = min(d0 + DPW, N_);
    const int pw0 = off[d0];
    const int pw1 = off[d1];

    int d = d0;
    int e1 = off[d0 + 1];
    float acc = 0.f;
    int buf = 0;

    // stage chunk 0
    {
        const int m = min(CHUNK, pw1 - pw0);
#pragma unroll
        for (int j = 0; j < 2; ++j) {
            const int f = lane + 64 * j;
            float4 v = make_float4(0.f, 0.f, 0.f, 0.f);
            if (f < m * 4) v = *(const float4*)&ea_s[(size_t)pw0 * 16 + f * 4];
            *(float4*)&s_ea[w][0][f * 4] = v;
        }
        if (lane < CHUNK)
            s_src[w][0][lane] = (lane < m) ? src_s[pw0 + lane] : 0;
    }
    __builtin_amdgcn_wave_barrier();

    for (int cp = pw0; cp < pw1; cp += CHUNK) {
        const int m = min(CHUNK, pw1 - cp);
        const int np = cp + CHUNK;
        const int nm = min(CHUNK, pw1 - np);   // may be <= 0

        // prefetch next chunk into registers (consumed after compute)
        float4 pre0 = make_float4(0.f, 0.f, 0.f, 0.f), pre1 = pre0;
        int psrc = 0;
        if (nm > 0) {
            { int f = lane;      if (f < nm * 4) pre0 = *(const float4*)&ea_s[(size_t)np * 16 + f * 4]; }
            { int f = lane + 64; if (f < nm * 4) pre1 = *(const float4*)&ea_s[(size_t)np * 16 + f * 4]; }
            if (lane < nm) psrc = src_s[np + lane];
        }

        // issue all gathers for the current chunk (OOB entries gather x[0])
        float xr[CHUNK];
#pragma unroll
        for (int i = 0; i < CHUNK; ++i) {
            const int s = s_src[w][buf][i];           // broadcast ds_read
            xr[i] = x[(size_t)s * CI + ln];
        }

        // compute: dot(ea_row, wcol) per edge, uniform dest-boundary flush
#pragma unroll
        for (int i = 0; i < CHUNK; ++i) {
            if (i >= m) break;
            while (cp + i == e1) {
                if (lane < CI) agg[(size_t)d * CI + lane] = acc;
                acc = 0.f; ++d;
                e1 = off[d + 1];
            }
            const float* er = &s_ea[w][buf][i * 16];
            float dotv = beL;
#pragma unroll
            for (int k = 0; k < 16; k += 4) {
                float4 ev = *(const float4*)&er[k];    // broadcast ds_read_b128
                dotv += ev.x * wcol[k] + ev.y * wcol[k + 1]
                      + ev.z * wcol[k + 2] + ev.w * wcol[k + 3];
            }
            float mm = xr[i] + dotv;
            acc += (mm > 0.f ? mm : 0.f);
        }

        // commit prefetch to the alternate buffer
        if (nm > 0) {
            *(float4*)&s_ea[w][buf ^ 1][lane * 4] = pre0;
            *(float4*)&s_ea[w][buf ^ 1][(lane + 64) * 4] = pre1;
            if (lane < CHUNK) s_src[w][buf ^ 1][lane] = psrc;
        }
        __builtin_amdgcn_wave_barrier();
        buf ^= 1;
    }

    // flush current dest + trailing zero-degree dests
    while (d < d1) {
        if (lane < CI) agg[(size_t)d * CI + lane] = acc;
        acc = 0.f; ++d;
    }
}

// ---------------------------------------------------------------------------
// Node GEMM (round 4/5): per-block partial BN stats, float4 staging.
// ---------------------------------------------------------------------------
template<int CI, int MODE>
__global__ __launch_bounds__(256, 4) void node_gemm(
    const float* __restrict__ in,
    const float* __restrict__ agg,   // MODE 0
    const float* __restrict__ eps,   // MODE 0
    const float* __restrict__ g1,    // MODE 1
    const float* __restrict__ bt1,   // MODE 1
    const float* __restrict__ stIn,  // MODE 1
    const float* __restrict__ W, const float* __restrict__ bias_,
    float* __restrict__ outbuf, float* __restrict__ partial)
{
    __shared__ __align__(16) float a_lds[64][CI + 4];
    __shared__ __align__(16) float w_lds[CI][68];
    __shared__ float s_sc[64], s_sh[64];
    const int t = threadIdx.x;
    const int n0 = blockIdx.x * 64;
    constexpr int QR = CI / 4;

    if (MODE == 1) {
        if (t < 64) {
            float mean = stIn[t] * (1.0f / N_);
            float var  = stIn[64 + t] * (1.0f / N_) - mean * mean;
            float sc = g1[t] * rsqrtf(var + 1e-5f);
            s_sc[t] = sc;
            s_sh[t] = bt1[t] - mean * sc;
        }
        __syncthreads();
    }

    if (MODE == 0) {
        const float hs = 1.0f + eps[0];
        for (int f = t; f < 64 * QR; f += 256) {
            int i = f / QR, q = f - i * QR;
            int n = n0 + i;
            float4 val = make_float4(0.f, 0.f, 0.f, 0.f);
            if (n < N_) {
                float4 xa = *(const float4*)&in[(size_t)n * CI + q * 4];
                float4 ag = *(const float4*)&agg[(size_t)n * CI + q * 4];
                val = make_float4(hs * xa.x + ag.x, hs * xa.y + ag.y,
                                  hs * xa.z + ag.z, hs * xa.w + ag.w);
            }
            *(float4*)&a_lds[i][q * 4] = val;
        }
    } else {
        for (int f = t; f < 64 * QR; f += 256) {
            int i = f / QR, q = f - i * QR;
            int n = n0 + i;
            float4 val = make_float4(0.f, 0.f, 0.f, 0.f);
            if (n < N_) {
                float4 uv = *(const float4*)&in[(size_t)n * CI + q * 4];
                int c = q * 4;
                val = make_float4(leaky_(uv.x * s_sc[c]     + s_sh[c]),
                                  leaky_(uv.y * s_sc[c + 1] + s_sh[c + 1]),
                                  leaky_(uv.z * s_sc[c + 2] + s_sh[c + 2]),
                                  leaky_(uv.w * s_sc[c + 3] + s_sh[c + 3]));
            }
            *(float4*)&a_lds[i][q * 4] = val;
        }
    }
    for (int f = t; f < CI * 16; f += 256) {
        int k = f >> 4, cq = f & 15;
        *(float4*)&w_lds[k][cq * 4] = *(const float4*)&W[k * 64 + cq * 4];
    }
    __syncthreads();

    const int tr = t & 15;
    const int c0 = (t >> 4) * 4;
    float acc[4][4] = {};
#pragma unroll 2
    for (int k = 0; k < CI; k += 4) {
        float ar[4][4];
#pragma unroll
        for (int j = 0; j < 4; ++j)
            *(float4*)&ar[j][0] = *(const float4*)&a_lds[tr + 16 * j][k];
#pragma unroll
        for (int kk = 0; kk < 4; ++kk) {
            float4 b = *(const float4*)&w_lds[k + kk][c0];
#pragma unroll
            for (int j = 0; j < 4; ++j) {
                acc[j][0] += ar[j][kk] * b.x;
                acc[j][1] += ar[j][kk] * b.y;
                acc[j][2] += ar[j][kk] * b.z;
                acc[j][3] += ar[j][kk] * b.w;
            }
        }
    }

    const float4 bb = *(const float4*)&bias_[c0];
    const float bias[4] = { bb.x, bb.y, bb.z, bb.w };
    float ls[4] = {}, lq[4] = {};
#pragma unroll
    for (int j = 0; j < 4; ++j) {
        int n = n0 + tr + 16 * j;
        if (n < N_) {
            float o[4];
#pragma unroll
            for (int cc = 0; cc < 4; ++cc) {
                o[cc] = acc[j][cc] + bias[cc];
                ls[cc] += o[cc];
                lq[cc] += o[cc] * o[cc];
            }
            *(float4*)&outbuf[(size_t)n * 64 + c0] = make_float4(o[0], o[1], o[2], o[3]);
        }
    }
#pragma unroll
    for (int m = 1; m <= 8; m <<= 1) {
#pragma unroll
        for (int cc = 0; cc < 4; ++cc) {
            ls[cc] += __shfl_xor(ls[cc], m);
            lq[cc] += __shfl_xor(lq[cc], m);
        }
    }
    if (tr == 0) {
#pragma unroll
        for (int cc = 0; cc < 4; ++cc) {
            partial[(size_t)(c0 + cc) * NBLK + blockIdx.x]      = ls[cc];
            partial[(size_t)(64 + c0 + cc) * NBLK + blockIdx.x] = lq[cc];
        }
    }
}

__global__ __launch_bounds__(256) void finalize_stats(
    const float* __restrict__ partial, float* __restrict__ stats)
{
    const int c = blockIdx.x;
    const int t = threadIdx.x;
    float s = 0.f;
    for (int b = t; b < NBLK; b += 256) s += partial[(size_t)c * NBLK + b];
    __shared__ float red[256];
    red[t] = s; __syncthreads();
    for (int o = 128; o > 0; o >>= 1) { if (t < o) red[t] += red[t + o]; __syncthreads(); }
    if (t == 0) stats[c] = red[0];
}

// ---------------------------------------------------------------------------
__global__ __launch_bounds__(256) void apply_bn_leaky(
    const float* __restrict__ v, const float* __restrict__ st,
    const float* __restrict__ g, const float* __restrict__ b,
    float* __restrict__ xout)
{
    size_t idx = ((size_t)blockIdx.x * 256 + threadIdx.x) * 4;
    if (idx >= (size_t)N_ * 64) return;
    int c0 = (int)(idx & 63);
    float4 vv = *(const float4*)&v[idx];
    float vi[4] = { vv.x, vv.y, vv.z, vv.w };
    float o[4];
#pragma unroll
    for (int cc = 0; cc < 4; ++cc) {
        int c = c0 + cc;
        float mean = st[c] * (1.0f / N_);
        float var  = st[64 + c] * (1.0f / N_) - mean * mean;
        float sc = g[c] * rsqrtf(var + 1e-5f);
        float sh = b[c] - mean * sc;
        o[cc] = leaky_(vi[cc] * sc + sh);
    }
    *(float4*)&xout[idx] = make_float4(o[0], o[1], o[2], o[3]);
}

// ---------------------------------------------------------------------------
__global__ __launch_bounds__(256) void pool_kernel(
    const float* __restrict__ x, float* __restrict__ pool)
{
    const int c = threadIdx.x & 63;
    const int g = blockIdx.x * 4 + (threadIdx.x >> 6);
    const float* p = x + (size_t)g * 50 * 64 + c;
    float s = 0.f;
#pragma unroll
    for (int j = 0; j < 50; ++j) s += p[(size_t)j * 64];
    pool[(size_t)g * 64 + c] = s;
}

// g0[g][c] = pool[g] @ W0b + b0  (W0b = W0 rows 64..127). 2 graphs/block.
__global__ __launch_bounds__(256) void pool_mlp0(
    const float* __restrict__ pool, const float* __restrict__ W0,
    const float* __restrict__ b0, float* __restrict__ g0)
{
    const int t = threadIdx.x;
    const int g = blockIdx.x * 2 + (t >> 7);
    const int c = t & 127;
    float s = b0[c];
    const float* pr = pool + (size_t)g * 64;
#pragma unroll 4
    for (int k = 0; k < 64; ++k)
        s += pr[k] * W0[(size_t)(64 + k) * 128 + c];
    g0[(size_t)g * 128 + c] = s;
}

// ---------------------------------------------------------------------------
// Fused MLP head: h1 = leaky(x@W0a + g0[n/50]); h2 = leaky(h1@W1 + b1);
// out = h2@Wf + bf.  128 nodes/block, 256 threads, 8x8 micro-tile.
// ---------------------------------------------------------------------------
__global__ __launch_bounds__(256, 2) void mlp_kernel(
    const float* __restrict__ x, const float* __restrict__ g0,
    const float* __restrict__ W0,
    const float* __restrict__ W1, const float* __restrict__ b1,
    const float* __restrict__ Wf, const float* __restrict__ bf,
    float* __restrict__ out)
{
    __shared__ __align__(16) float a_lds[128][132];   // 67.6 KB
    __shared__ __align__(16) float w_lds[16][132];    // 8.4 KB
    __shared__ __align__(16) float sWfT[2][128];
    __shared__ int sbid[128];
    const int t = threadIdx.x;
    const int n0 = blockIdx.x * 128;

    for (int f = t; f < 128 * 16; f += 256) {
        int i = f >> 4, q = f & 15;
        int n = n0 + i;
        float4 val = make_float4(0.f, 0.f, 0.f, 0.f);
        if (n < N_) val = *(const float4*)&x[(size_t)n * 64 + q * 4];
        *(float4*)&a_lds[i][q * 4] = val;
    }
    if (t < 128) {
        int n = n0 + t;
        sbid[t] = (n < N_) ? (n / 50) : (G_ - 1);
        sWfT[0][t] = Wf[t * 2];
        sWfT[1][t] = Wf[t * 2 + 1];
    }

    const int tr = t & 15;
    const int c0 = (t >> 4) * 8;
    float acc[8][8];

#pragma unroll
    for (int j = 0; j < 8; ++j)
#pragma unroll
        for (int cc = 0; cc < 8; ++cc) acc[j][cc] = 0.f;

    for (int kc = 0; kc < 64; kc += 16) {
        __syncthreads();
        for (int f = t; f < 16 * 32; f += 256) {
            int k = f >> 5, cq = f & 31;
            *(float4*)&w_lds[k][cq * 4] = *(const float4*)&W0[(size_t)(kc + k) * 128 + cq * 4];
        }
        __syncthreads();
        for (int k = 0; k < 16; k += 4) {
            float ar[8][4];
#pragma unroll
            for (int j = 0; j < 8; ++j)
                *(float4*)&ar[j][0] = *(const float4*)&a_lds[tr + 16 * j][kc + k];
#pragma unroll
            for (int kk = 0; kk < 4; ++kk) {
                float4 bA = *(const float4*)&w_lds[k + kk][c0];
                float4 bB = *(const float4*)&w_lds[k + kk][c0 + 4];
#pragma unroll
                for (int j = 0; j < 8; ++j) {
                    acc[j][0] += ar[j][kk] * bA.x;
                    acc[j][1] += ar[j][kk] * bA.y;
                    acc[j][2] += ar[j][kk] * bA.z;
                    acc[j][3] += ar[j][kk] * bA.w;
                    acc[j][4] += ar[j][kk] * bB.x;
                    acc[j][5] += ar[j][kk] * bB.y;
                    acc[j][6] += ar[j][kk] * bB.z;
                    acc[j][7] += ar[j][kk] * bB.w;
                }
            }
        }
    }
    __syncthreads();
#pragma unroll
    for (int j = 0; j < 8; ++j) {
        int row = tr + 16 * j;
        const float* gr = g0 + (size_t)sbid[row] * 128;
        float4 gA = *(const float4*)&gr[c0];
        float4 gB = *(const float4*)&gr[c0 + 4];
        float o[8] = { acc[j][0] + gA.x, acc[j][1] + gA.y, acc[j][2] + gA.z, acc[j][3] + gA.w,
                       acc[j][4] + gB.x, acc[j][5] + gB.y, acc[j][6] + gB.z, acc[j][7] + gB.w };
#pragma unroll
        for (int cc = 0; cc < 8; ++cc) o[cc] = leaky_(o[cc]);
        *(float4*)&a_lds[row][c0]     = make_float4(o[0], o[1], o[2], o[3]);
        *(float4*)&a_lds[row][c0 + 4] = make_float4(o[4], o[5], o[6], o[7]);
    }

#pragma unroll
    for (int j = 0; j < 8; ++j)
#pragma unroll
        for (int cc = 0; cc < 8; ++cc) acc[j][cc] = 0.f;

    for (int kc = 0; kc < 128; kc += 16) {
        __syncthreads();
        for (int f = t; f < 16 * 32; f += 256) {
            int k = f >> 5, cq = f & 31;
            *(float4*)&w_lds[k][cq * 4] = *(const float4*)&W1[(size_t)(kc + k) * 128 + cq * 4];
        }
        __syncthreads();
        for (int k = 0; k < 16; k += 4) {
            float ar[8][4];
#pragma unroll
            for (int j = 0; j < 8; ++j)
                *(float4*)&ar[j][0] = *(const float4*)&a_lds[tr + 16 * j][kc + k];
#pragma unroll
            for (int kk = 0; kk < 4; ++kk) {
                float4 bA = *(const float4*)&w_lds[k + kk][c0];
                float4 bB = *(const float4*)&w_lds[k + kk][c0 + 4];
#pragma unroll
                for (int j = 0; j < 8; ++j) {
                    acc[j][0] += ar[j][kk] * bA.x;
                    acc[j][1] += ar[j][kk] * bA.y;
                    acc[j][2] += ar[j][kk] * bA.z;
                    acc[j][3] += ar[j][kk] * bA.w;
                    acc[j][4] += ar[j][kk] * bB.x;
                    acc[j][5] += ar[j][kk] * bB.y;
                    acc[j][6] += ar[j][kk] * bB.z;
                    acc[j][7] += ar[j][kk] * bB.w;
                }
            }
        }
    }
    __syncthreads();
    {
        float4 bb0 = *(const float4*)&b1[c0];
        float4 bb1 = *(const float4*)&b1[c0 + 4];
        float bias[8] = { bb0.x, bb0.y, bb0.z, bb0.w, bb1.x, bb1.y, bb1.z, bb1.w };
#pragma unroll
        for (int j = 0; j < 8; ++j) {
            int row = tr + 16 * j;
            float o[8];
#pragma unroll
            for (int cc = 0; cc < 8; ++cc) o[cc] = leaky_(acc[j][cc] + bias[cc]);
            *(float4*)&a_lds[row][c0]     = make_float4(o[0], o[1], o[2], o[3]);
            *(float4*)&a_lds[row][c0 + 4] = make_float4(o[4], o[5], o[6], o[7]);
        }
    }
    __syncthreads();

    {
        int i = t >> 1, c = t & 1;
        int n = n0 + i;
        if (n < N_) {
            float s = bf[c];
            for (int k = 0; k < 128; k += 4) {
                float4 av = *(const float4*)&a_lds[i][k];
                float4 wv = *(const float4*)&sWfT[c][k];
                s += av.x * wv.x + av.y * wv.y + av.z * wv.z + av.w * wv.w;
            }
            out[(size_t)n * 2 + c] = s;
        }
    }
}

// ---------------------------------------------------------------------------
extern "C" void kernel_launch(void* const* d_in, const int* in_sizes, int n_in,
                              void* d_out, int out_size, void* d_ws, size_t ws_size,
                              hipStream_t stream)
{
    (void)in_sizes; (void)n_in; (void)out_size; (void)ws_size;

    const float* x0    = (const float*)d_in[0];
    const int*   eidx  = (const int*)d_in[1];
    const float* eattr = (const float*)d_in[2];
    const float* L[3][11];
    for (int l = 0; l < 3; ++l)
        for (int j = 0; j < 11; ++j)
            L[l][j] = (const float*)d_in[4 + l * 11 + j];
    const float* mlp0W = (const float*)d_in[37];
    const float* mlp0b = (const float*)d_in[38];
    const float* mlp1W = (const float*)d_in[39];
    const float* mlp1b = (const float*)d_in[40];
    const float* finW  = (const float*)d_in[41];
    const float* finb  = (const float*)d_in[42];
    float* out = (float*)d_out;

    float* ws    = (float*)d_ws;
    float* agg   = ws;                          // N*64 (reused as v after gemm1)
    float* u     = agg  + (size_t)N_ * 64;      // N*64
    float* xbuf  = u    + (size_t)N_ * 64;      // N*64
    float* pool  = xbuf + (size_t)N_ * 64;      // G*64
    float* g0    = pool + (size_t)G_ * 64;      // G*128
    float* stats = g0   + (size_t)G_ * 128;     // 768
    float* partial = stats + 768;               // 128*NBLK
    int*   off   = (int*)(partial + 128 * NBLK); // N+1 (+1 pad)
    int*   cnt   = off + (N_ + 2);              // N
    int*   bsum  = cnt + N_;                    // 256
    int*   bpref = bsum + 256;                  // 256
    int*   rank  = bpref + 256;                 // E
    int*   src_s = rank + E_;                   // E
    float* ea_s  = (float*)((((uintptr_t)(src_s + E_)) + 63) & ~(uintptr_t)63); // E*16, 64B aligned
    float* v = agg;

    const int* src = eidx;
    const int* dst = eidx + E_;
    const int GB = NBLK;

    // ---- counting sort of edges by dst (rank-based, atomic-free placement) ----
    hipMemsetAsync(cnt, 0, (size_t)N_ * sizeof(int), stream);
    hist_rank_kernel<<<2048, 256, 0, stream>>>(dst, cnt, rank);
    scanA<<<SCAN_NB, 256, 0, stream>>>(cnt, bsum);
    scanB<<<1, 256, 0, stream>>>(bsum, bpref);
    scanC<<<SCAN_NB, 256, 0, stream>>>(cnt, off, bpref);
    place_kernel<<<2048, 256, 0, stream>>>(src, dst, rank, off, eattr, src_s, ea_s);

    const int AGGB = ((N_ + DPW - 1) / DPW + 3) / 4 + 1;

    for (int l = 0; l < 3; ++l) {
        float* s1 = stats + (2 * l) * 128;
        float* s2 = stats + (2 * l + 1) * 128;
        if (l == 0) {
            agg_sorted<40><<<AGGB, 256, 0, stream>>>(ea_s, src_s, off, L[0][1], L[0][2], x0, agg);
            node_gemm<40, 0><<<GB, 256, 0, stream>>>(x0, agg, L[0][0], nullptr, nullptr, nullptr,
                                                     L[0][3], L[0][4], u, partial);
        } else {
            agg_sorted<64><<<AGGB, 256, 0, stream>>>(ea_s, src_s, off, L[l][1], L[l][2], xbuf, agg);
            node_gemm<64, 0><<<GB, 256, 0, stream>>>(xbuf, agg, L[l][0], nullptr, nullptr, nullptr,
                                                     L[l][3], L[l][4], u, partial);
        }
        finalize_stats<<<128, 256, 0, stream>>>(partial, s1);
        node_gemm<64, 1><<<GB, 256, 0, stream>>>(u, nullptr, nullptr, L[l][5], L[l][6], s1,
                                                 L[l][7], L[l][8], v, partial);
        finalize_stats<<<128, 256, 0, stream>>>(partial, s2);
        apply_bn_leaky<<<6250, 256, 0, stream>>>(v, s2, L[l][9], L[l][10], xbuf);
    }

    // ---- pool + per-graph mlp0 term + fused MLP head ----
    pool_kernel<<<G_ / 4, 256, 0, stream>>>(xbuf, pool);
    pool_mlp0<<<G_ / 2, 256, 0, stream>>>(pool, mlp0W, mlp0b, g0);
    mlp_kernel<<<(N_ + 127) / 128, 256, 0, stream>>>(xbuf, g0, mlp0W,
                                                     mlp1W, mlp1b, finW, finb, out);
}

// Round 11
// 905.327 us; speedup vs baseline: 1.4863x; 1.1255x over previous
//
#include <hip/hip_runtime.h>

// GINE-GNN forward on MI355X. Round 11:
//  - agg_sorted was LDS-broadcast-bound (E x 64 lanes x 64B = 6.5 GB/layer of
//    ds_read, ~95us floor). Store sorted edge_attr as f16 (place converts),
//    stage f16 chunks, dot via 8x v_dot2_f32_f16 -> LDS bytes and dot VALU
//    both halved. f32 accumulate keeps error ~1e-3 (threshold 0.24).

#define N_  100000
#define E_  1600000
#define G_  2000
#define SCAN_NB 196          // ceil(N / 512)
#define NBLK 1563            // ceil(N / 64)

typedef _Float16 half2v __attribute__((ext_vector_type(2)));

__device__ __forceinline__ float leaky_(float z) { return z >= 0.f ? z : 0.01f * z; }

__device__ __forceinline__ half2v u2h(unsigned u) {
    union { unsigned u; half2v h; } c; c.u = u; return c.h;
}

__device__ __forceinline__ float dot2_(half2v a, half2v b, float c) {
#if __has_builtin(__builtin_amdgcn_fdot2)
    return __builtin_amdgcn_fdot2(a, b, c, false);
#else
    return c + (float)a.x * (float)b.x + (float)a.y * (float)b.y;
#endif
}

// ---------------------------------------------------------------------------
// Counting sort of edges by dst: hist(+rank) -> scanA/B/C -> place(f16 cvt).
// ---------------------------------------------------------------------------
__global__ __launch_bounds__(256) void hist_rank_kernel(
    const int* __restrict__ dst, int* __restrict__ cnt, int* __restrict__ rank)
{
#pragma unroll 4
    for (int e = blockIdx.x * 256 + threadIdx.x; e < E_; e += gridDim.x * 256)
        rank[e] = atomicAdd(&cnt[dst[e]], 1);
}

__global__ __launch_bounds__(256) void scanA(
    const int* __restrict__ cnt, int* __restrict__ blocksum)
{
    __shared__ int s[256];
    const int t = threadIdx.x, b = blockIdx.x;
    const int i0 = (b * 256 + t) * 2;
    int v = 0;
    if (i0 < N_) v += cnt[i0];
    if (i0 + 1 < N_) v += cnt[i0 + 1];
    s[t] = v; __syncthreads();
    for (int o = 128; o > 0; o >>= 1) { if (t < o) s[t] += s[t + o]; __syncthreads(); }
    if (t == 0) blocksum[b] = s[0];
}

__global__ __launch_bounds__(256) void scanB(
    const int* __restrict__ blocksum, int* __restrict__ blockpref)
{
    __shared__ int s[256];
    const int t = threadIdx.x;
    int v = (t < SCAN_NB) ? blocksum[t] : 0;
    s[t] = v; __syncthreads();
    for (int o = 1; o < 256; o <<= 1) {
        int u = (t >= o) ? s[t - o] : 0;
        __syncthreads(); s[t] += u; __syncthreads();
    }
    blockpref[t] = s[t] - v;   // exclusive
}

__global__ __launch_bounds__(256) void scanC(
    const int* __restrict__ cnt, int* __restrict__ off,
    const int* __restrict__ blockpref)
{
    __shared__ int s[256];
    const int t = threadIdx.x, b = blockIdx.x;
    const int i0 = (b * 256 + t) * 2;
    int v0 = (i0 < N_) ? cnt[i0] : 0;
    int v1 = (i0 + 1 < N_) ? cnt[i0 + 1] : 0;
    int pv = v0 + v1;
    s[t] = pv; __syncthreads();
    for (int o = 1; o < 256; o <<= 1) {
        int u = (t >= o) ? s[t - o] : 0;
        __syncthreads(); s[t] += u; __syncthreads();
    }
    int run = blockpref[b] + s[t] - pv;
    if (i0 < N_) {
        off[i0] = run; run += v0;
        if (i0 + 1 < N_) off[i0 + 1] = run;
    }
    if (b == 0 && t == 0) off[N_] = E_;
}

// place: p = off[dst]+rank (no atomic). src_s[p] 4B; ea_h[p] = f16 row (32B).
__global__ __launch_bounds__(256) void place_kernel(
    const int* __restrict__ src, const int* __restrict__ dst,
    const int* __restrict__ rank, const int* __restrict__ off,
    const float* __restrict__ edge_attr,
    int* __restrict__ src_s, unsigned short* __restrict__ ea_h)
{
#pragma unroll 2
    for (int e = blockIdx.x * 256 + threadIdx.x; e < E_; e += gridDim.x * 256) {
        const int p = off[dst[e]] + rank[e];
        src_s[p] = src[e];
        const float4* __restrict__ ea = (const float4*)(edge_attr + (size_t)e * 16);
        float4 a0 = ea[0], a1 = ea[1], a2 = ea[2], a3 = ea[3];
        union { uint4 u4[2]; half2v h[8]; } cv;
        cv.h[0] = half2v{(_Float16)a0.x, (_Float16)a0.y};
        cv.h[1] = half2v{(_Float16)a0.z, (_Float16)a0.w};
        cv.h[2] = half2v{(_Float16)a1.x, (_Float16)a1.y};
        cv.h[3] = half2v{(_Float16)a1.z, (_Float16)a1.w};
        cv.h[4] = half2v{(_Float16)a2.x, (_Float16)a2.y};
        cv.h[5] = half2v{(_Float16)a2.z, (_Float16)a2.w};
        cv.h[6] = half2v{(_Float16)a3.x, (_Float16)a3.y};
        cv.h[7] = half2v{(_Float16)a3.z, (_Float16)a3.w};
        uint4* __restrict__ eo = (uint4*)(ea_h + (size_t)p * 16);
        eo[0] = cv.u4[0]; eo[1] = cv.u4[1];
    }
}

// ---------------------------------------------------------------------------
// Sorted-edge aggregation: one wave owns DPW consecutive destinations.
// f16 ea rows: chunk = 32 edges x 32B = 1KB, staged by ONE uint4/lane;
// per edge 2 broadcast b128 reads + 8 fdot2 (f32 acc).
// ---------------------------------------------------------------------------
#define DPW 13
#define CHUNK 32

template<int CI>
__global__ __launch_bounds__(256, 4) void agg_sorted(
    const unsigned short* __restrict__ ea_h,   // [E,16] f16, sorted by dst
    const int* __restrict__ src_s,             // [E] sorted by dst
    const int* __restrict__ off,
    const float* __restrict__ We, const float* __restrict__ be,
    const float* __restrict__ x, float* __restrict__ agg)
{
    __shared__ __align__(16) unsigned s_ea[4][2][CHUNK * 8];   // 8 KB
    __shared__ int s_src[4][2][CHUNK];                         // 1 KB
    const int t = threadIdx.x;
    const int lane = t & 63;
    const int w = t >> 6;
    const int wid = __builtin_amdgcn_readfirstlane(blockIdx.x * 4 + w);

    half2v wh[8];
#pragma unroll
    for (int k = 0; k < 8; ++k) wh[k] = half2v{(_Float16)0.f, (_Float16)0.f};
    float beL = 0.f;
    if (lane < CI) {
#pragma unroll
        for (int k = 0; k < 8; ++k)
            wh[k] = half2v{(_Float16)We[(2 * k) * CI + lane],
                           (_Float16)We[(2 * k + 1) * CI + lane]};
        beL = be[lane];
    }
    const int ln = (lane < CI) ? lane : 0;

    const int d0 = wid * DPW;
    if (d0 >= N_) return;
    const int d1 = min(d0 + DPW, N_);
    const int pw0 = off[d0];
    const int pw1 = off[d1];

    int d = d0;
    int e1 = off[d0 + 1];
    float acc = 0.f;
    int buf = 0;

    // stage chunk 0 (chunk = m*2 uint4s; lane stages uint4 #lane)
    {
        const int m = min(CHUNK, pw1 - pw0);
        uint4 v = make_uint4(0, 0, 0, 0);
        if (lane < m * 2) v = ((const uint4*)(ea_h + (size_t)pw0 * 16))[lane];
        *(uint4*)&s_ea[w][0][lane * 4] = v;
        if (lane < CHUNK)
            s_src[w][0][lane] = (lane < m) ? src_s[pw0 + lane] : 0;
    }
    __builtin_amdgcn_wave_barrier();

    for (int cp = pw0; cp < pw1; cp += CHUNK) {
        const int m = min(CHUNK, pw1 - cp);
        const int np = cp + CHUNK;
        const int nm = min(CHUNK, pw1 - np);   // may be <= 0

        // prefetch next chunk into registers (consumed after compute)
        uint4 pre = make_uint4(0, 0, 0, 0);
        int psrc = 0;
        if (nm > 0) {
            if (lane < nm * 2) pre = ((const uint4*)(ea_h + (size_t)np * 16))[lane];
            if (lane < nm) psrc = src_s[np + lane];
        }

        // issue all gathers for the current chunk (OOB entries gather x[0])
        float xr[CHUNK];
#pragma unroll
        for (int i = 0; i < CHUNK; ++i) {
            const int s = s_src[w][buf][i];           // broadcast ds_read
            xr[i] = x[(size_t)s * CI + ln];
        }

        // compute: f16 dot via fdot2, uniform dest-boundary flush
#pragma unroll
        for (int i = 0; i < CHUNK; ++i) {
            if (i >= m) break;
            while (cp + i == e1) {
                if (lane < CI) agg[(size_t)d * CI + lane] = acc;
                acc = 0.f; ++d;
                e1 = off[d + 1];
            }
            const unsigned* er = &s_ea[w][buf][i * 8];
            uint4 e0 = *(const uint4*)&er[0];          // broadcast ds_read_b128
            uint4 e2 = *(const uint4*)&er[4];
            float dotv = beL;
            dotv = dot2_(u2h(e0.x), wh[0], dotv);
            dotv = dot2_(u2h(e0.y), wh[1], dotv);
            dotv = dot2_(u2h(e0.z), wh[2], dotv);
            dotv = dot2_(u2h(e0.w), wh[3], dotv);
            dotv = dot2_(u2h(e2.x), wh[4], dotv);
            dotv = dot2_(u2h(e2.y), wh[5], dotv);
            dotv = dot2_(u2h(e2.z), wh[6], dotv);
            dotv = dot2_(u2h(e2.w), wh[7], dotv);
            float mm = xr[i] + dotv;
            acc += (mm > 0.f ? mm : 0.f);
        }

        // commit prefetch to the alternate buffer
        if (nm > 0) {
            *(uint4*)&s_ea[w][buf ^ 1][lane * 4] = pre;
            if (lane < CHUNK) s_src[w][buf ^ 1][lane] = psrc;
        }
        __builtin_amdgcn_wave_barrier();
        buf ^= 1;
    }

    // flush current dest + trailing zero-degree dests
    while (d < d1) {
        if (lane < CI) agg[(size_t)d * CI + lane] = acc;
        acc = 0.f; ++d;
    }
}

// ---------------------------------------------------------------------------
// Node GEMM (round 4/5): per-block partial BN stats, float4 staging.
// ---------------------------------------------------------------------------
template<int CI, int MODE>
__global__ __launch_bounds__(256, 4) void node_gemm(
    const float* __restrict__ in,
    const float* __restrict__ agg,   // MODE 0
    const float* __restrict__ eps,   // MODE 0
    const float* __restrict__ g1,    // MODE 1
    const float* __restrict__ bt1,   // MODE 1
    const float* __restrict__ stIn,  // MODE 1
    const float* __restrict__ W, const float* __restrict__ bias_,
    float* __restrict__ outbuf, float* __restrict__ partial)
{
    __shared__ __align__(16) float a_lds[64][CI + 4];
    __shared__ __align__(16) float w_lds[CI][68];
    __shared__ float s_sc[64], s_sh[64];
    const int t = threadIdx.x;
    const int n0 = blockIdx.x * 64;
    constexpr int QR = CI / 4;

    if (MODE == 1) {
        if (t < 64) {
            float mean = stIn[t] * (1.0f / N_);
            float var  = stIn[64 + t] * (1.0f / N_) - mean * mean;
            float sc = g1[t] * rsqrtf(var + 1e-5f);
            s_sc[t] = sc;
            s_sh[t] = bt1[t] - mean * sc;
        }
        __syncthreads();
    }

    if (MODE == 0) {
        const float hs = 1.0f + eps[0];
        for (int f = t; f < 64 * QR; f += 256) {
            int i = f / QR, q = f - i * QR;
            int n = n0 + i;
            float4 val = make_float4(0.f, 0.f, 0.f, 0.f);
            if (n < N_) {
                float4 xa = *(const float4*)&in[(size_t)n * CI + q * 4];
                float4 ag = *(const float4*)&agg[(size_t)n * CI + q * 4];
                val = make_float4(hs * xa.x + ag.x, hs * xa.y + ag.y,
                                  hs * xa.z + ag.z, hs * xa.w + ag.w);
            }
            *(float4*)&a_lds[i][q * 4] = val;
        }
    } else {
        for (int f = t; f < 64 * QR; f += 256) {
            int i = f / QR, q = f - i * QR;
            int n = n0 + i;
            float4 val = make_float4(0.f, 0.f, 0.f, 0.f);
            if (n < N_) {
                float4 uv = *(const float4*)&in[(size_t)n * CI + q * 4];
                int c = q * 4;
                val = make_float4(leaky_(uv.x * s_sc[c]     + s_sh[c]),
                                  leaky_(uv.y * s_sc[c + 1] + s_sh[c + 1]),
                                  leaky_(uv.z * s_sc[c + 2] + s_sh[c + 2]),
                                  leaky_(uv.w * s_sc[c + 3] + s_sh[c + 3]));
            }
            *(float4*)&a_lds[i][q * 4] = val;
        }
    }
    for (int f = t; f < CI * 16; f += 256) {
        int k = f >> 4, cq = f & 15;
        *(float4*)&w_lds[k][cq * 4] = *(const float4*)&W[k * 64 + cq * 4];
    }
    __syncthreads();

    const int tr = t & 15;
    const int c0 = (t >> 4) * 4;
    float acc[4][4] = {};
#pragma unroll 2
    for (int k = 0; k < CI; k += 4) {
        float ar[4][4];
#pragma unroll
        for (int j = 0; j < 4; ++j)
            *(float4*)&ar[j][0] = *(const float4*)&a_lds[tr + 16 * j][k];
#pragma unroll
        for (int kk = 0; kk < 4; ++kk) {
            float4 b = *(const float4*)&w_lds[k + kk][c0];
#pragma unroll
            for (int j = 0; j < 4; ++j) {
                acc[j][0] += ar[j][kk] * b.x;
                acc[j][1] += ar[j][kk] * b.y;
                acc[j][2] += ar[j][kk] * b.z;
                acc[j][3] += ar[j][kk] * b.w;
            }
        }
    }

    const float4 bb = *(const float4*)&bias_[c0];
    const float bias[4] = { bb.x, bb.y, bb.z, bb.w };
    float ls[4] = {}, lq[4] = {};
#pragma unroll
    for (int j = 0; j < 4; ++j) {
        int n = n0 + tr + 16 * j;
        if (n < N_) {
            float o[4];
#pragma unroll
            for (int cc = 0; cc < 4; ++cc) {
                o[cc] = acc[j][cc] + bias[cc];
                ls[cc] += o[cc];
                lq[cc] += o[cc] * o[cc];
            }
            *(float4*)&outbuf[(size_t)n * 64 + c0] = make_float4(o[0], o[1], o[2], o[3]);
        }
    }
#pragma unroll
    for (int m = 1; m <= 8; m <<= 1) {
#pragma unroll
        for (int cc = 0; cc < 4; ++cc) {
            ls[cc] += __shfl_xor(ls[cc], m);
            lq[cc] += __shfl_xor(lq[cc], m);
        }
    }
    if (tr == 0) {
#pragma unroll
        for (int cc = 0; cc < 4; ++cc) {
            partial[(size_t)(c0 + cc) * NBLK + blockIdx.x]      = ls[cc];
            partial[(size_t)(64 + c0 + cc) * NBLK + blockIdx.x] = lq[cc];
        }
    }
}

__global__ __launch_bounds__(256) void finalize_stats(
    const float* __restrict__ partial, float* __restrict__ stats)
{
    const int c = blockIdx.x;
    const int t = threadIdx.x;
    float s = 0.f;
    for (int b = t; b < NBLK; b += 256) s += partial[(size_t)c * NBLK + b];
    __shared__ float red[256];
    red[t] = s; __syncthreads();
    for (int o = 128; o > 0; o >>= 1) { if (t < o) red[t] += red[t + o]; __syncthreads(); }
    if (t == 0) stats[c] = red[0];
}

// ---------------------------------------------------------------------------
__global__ __launch_bounds__(256) void apply_bn_leaky(
    const float* __restrict__ v, const float* __restrict__ st,
    const float* __restrict__ g, const float* __restrict__ b,
    float* __restrict__ xout)
{
    size_t idx = ((size_t)blockIdx.x * 256 + threadIdx.x) * 4;
    if (idx >= (size_t)N_ * 64) return;
    int c0 = (int)(idx & 63);
    float4 vv = *(const float4*)&v[idx];
    float vi[4] = { vv.x, vv.y, vv.z, vv.w };
    float o[4];
#pragma unroll
    for (int cc = 0; cc < 4; ++cc) {
        int c = c0 + cc;
        float mean = st[c] * (1.0f / N_);
        float var  = st[64 + c] * (1.0f / N_) - mean * mean;
        float sc = g[c] * rsqrtf(var + 1e-5f);
        float sh = b[c] - mean * sc;
        o[cc] = leaky_(vi[cc] * sc + sh);
    }
    *(float4*)&xout[idx] = make_float4(o[0], o[1], o[2], o[3]);
}

// ---------------------------------------------------------------------------
__global__ __launch_bounds__(256) void pool_kernel(
    const float* __restrict__ x, float* __restrict__ pool)
{
    const int c = threadIdx.x & 63;
    const int g = blockIdx.x * 4 + (threadIdx.x >> 6);
    const float* p = x + (size_t)g * 50 * 64 + c;
    float s = 0.f;
#pragma unroll
    for (int j = 0; j < 50; ++j) s += p[(size_t)j * 64];
    pool[(size_t)g * 64 + c] = s;
}

// g0[g][c] = pool[g] @ W0b + b0  (W0b = W0 rows 64..127). 2 graphs/block.
__global__ __launch_bounds__(256) void pool_mlp0(
    const float* __restrict__ pool, const float* __restrict__ W0,
    const float* __restrict__ b0, float* __restrict__ g0)
{
    const int t = threadIdx.x;
    const int g = blockIdx.x * 2 + (t >> 7);
    const int c = t & 127;
    float s = b0[c];
    const float* pr = pool + (size_t)g * 64;
#pragma unroll 4
    for (int k = 0; k < 64; ++k)
        s += pr[k] * W0[(size_t)(64 + k) * 128 + c];
    g0[(size_t)g * 128 + c] = s;
}

// ---------------------------------------------------------------------------
// Fused MLP head: h1 = leaky(x@W0a + g0[n/50]); h2 = leaky(h1@W1 + b1);
// out = h2@Wf + bf.  128 nodes/block, 256 threads, 8x8 micro-tile.
// ---------------------------------------------------------------------------
__global__ __launch_bounds__(256, 2) void mlp_kernel(
    const float* __restrict__ x, const float* __restrict__ g0,
    const float* __restrict__ W0,
    const float* __restrict__ W1, const float* __restrict__ b1,
    const float* __restrict__ Wf, const float* __restrict__ bf,
    float* __restrict__ out)
{
    __shared__ __align__(16) float a_lds[128][132];   // 67.6 KB
    __shared__ __align__(16) float w_lds[16][132];    // 8.4 KB
    __shared__ __align__(16) float sWfT[2][128];
    __shared__ int sbid[128];
    const int t = threadIdx.x;
    const int n0 = blockIdx.x * 128;

    for (int f = t; f < 128 * 16; f += 256) {
        int i = f >> 4, q = f & 15;
        int n = n0 + i;
        float4 val = make_float4(0.f, 0.f, 0.f, 0.f);
        if (n < N_) val = *(const float4*)&x[(size_t)n * 64 + q * 4];
        *(float4*)&a_lds[i][q * 4] = val;
    }
    if (t < 128) {
        int n = n0 + t;
        sbid[t] = (n < N_) ? (n / 50) : (G_ - 1);
        sWfT[0][t] = Wf[t * 2];
        sWfT[1][t] = Wf[t * 2 + 1];
    }

    const int tr = t & 15;
    const int c0 = (t >> 4) * 8;
    float acc[8][8];

#pragma unroll
    for (int j = 0; j < 8; ++j)
#pragma unroll
        for (int cc = 0; cc < 8; ++cc) acc[j][cc] = 0.f;

    for (int kc = 0; kc < 64; kc += 16) {
        __syncthreads();
        for (int f = t; f < 16 * 32; f += 256) {
            int k = f >> 5, cq = f & 31;
            *(float4*)&w_lds[k][cq * 4] = *(const float4*)&W0[(size_t)(kc + k) * 128 + cq * 4];
        }
        __syncthreads();
        for (int k = 0; k < 16; k += 4) {
            float ar[8][4];
#pragma unroll
            for (int j = 0; j < 8; ++j)
                *(float4*)&ar[j][0] = *(const float4*)&a_lds[tr + 16 * j][kc + k];
#pragma unroll
            for (int kk = 0; kk < 4; ++kk) {
                float4 bA = *(const float4*)&w_lds[k + kk][c0];
                float4 bB = *(const float4*)&w_lds[k + kk][c0 + 4];
#pragma unroll
                for (int j = 0; j < 8; ++j) {
                    acc[j][0] += ar[j][kk] * bA.x;
                    acc[j][1] += ar[j][kk] * bA.y;
                    acc[j][2] += ar[j][kk] * bA.z;
                    acc[j][3] += ar[j][kk] * bA.w;
                    acc[j][4] += ar[j][kk] * bB.x;
                    acc[j][5] += ar[j][kk] * bB.y;
                    acc[j][6] += ar[j][kk] * bB.z;
                    acc[j][7] += ar[j][kk] * bB.w;
                }
            }
        }
    }
    __syncthreads();
#pragma unroll
    for (int j = 0; j < 8; ++j) {
        int row = tr + 16 * j;
        const float* gr = g0 + (size_t)sbid[row] * 128;
        float4 gA = *(const float4*)&gr[c0];
        float4 gB = *(const float4*)&gr[c0 + 4];
        float o[8] = { acc[j][0] + gA.x, acc[j][1] + gA.y, acc[j][2] + gA.z, acc[j][3] + gA.w,
                       acc[j][4] + gB.x, acc[j][5] + gB.y, acc[j][6] + gB.z, acc[j][7] + gB.w };
#pragma unroll
        for (int cc = 0; cc < 8; ++cc) o[cc] = leaky_(o[cc]);
        *(float4*)&a_lds[row][c0]     = make_float4(o[0], o[1], o[2], o[3]);
        *(float4*)&a_lds[row][c0 + 4] = make_float4(o[4], o[5], o[6], o[7]);
    }

#pragma unroll
    for (int j = 0; j < 8; ++j)
#pragma unroll
        for (int cc = 0; cc < 8; ++cc) acc[j][cc] = 0.f;

    for (int kc = 0; kc < 128; kc += 16) {
        __syncthreads();
        for (int f = t; f < 16 * 32; f += 256) {
            int k = f >> 5, cq = f & 31;
            *(float4*)&w_lds[k][cq * 4] = *(const float4*)&W1[(size_t)(kc + k) * 128 + cq * 4];
        }
        __syncthreads();
        for (int k = 0; k < 16; k += 4) {
            float ar[8][4];
#pragma unroll
            for (int j = 0; j < 8; ++j)
                *(float4*)&ar[j][0] = *(const float4*)&a_lds[tr + 16 * j][kc + k];
#pragma unroll
            for (int kk = 0; kk < 4; ++kk) {
                float4 bA = *(const float4*)&w_lds[k + kk][c0];
                float4 bB = *(const float4*)&w_lds[k + kk][c0 + 4];
#pragma unroll
                for (int j = 0; j < 8; ++j) {
                    acc[j][0] += ar[j][kk] * bA.x;
                    acc[j][1] += ar[j][kk] * bA.y;
                    acc[j][2] += ar[j][kk] * bA.z;
                    acc[j][3] += ar[j][kk] * bA.w;
                    acc[j][4] += ar[j][kk] * bB.x;
                    acc[j][5] += ar[j][kk] * bB.y;
                    acc[j][6] += ar[j][kk] * bB.z;
                    acc[j][7] += ar[j][kk] * bB.w;
                }
            }
        }
    }
    __syncthreads();
    {
        float4 bb0 = *(const float4*)&b1[c0];
        float4 bb1 = *(const float4*)&b1[c0 + 4];
        float bias[8] = { bb0.x, bb0.y, bb0.z, bb0.w, bb1.x, bb1.y, bb1.z, bb1.w };
#pragma unroll
        for (int j = 0; j < 8; ++j) {
            int row = tr + 16 * j;
            float o[8];
#pragma unroll
            for (int cc = 0; cc < 8; ++cc) o[cc] = leaky_(acc[j][cc] + bias[cc]);
            *(float4*)&a_lds[row][c0]     = make_float4(o[0], o[1], o[2], o[3]);
            *(float4*)&a_lds[row][c0 + 4] = make_float4(o[4], o[5], o[6], o[7]);
        }
    }
    __syncthreads();

    {
        int i = t >> 1, c = t & 1;
        int n = n0 + i;
        if (n < N_) {
            float s = bf[c];
            for (int k = 0; k < 128; k += 4) {
                float4 av = *(const float4*)&a_lds[i][k];
                float4 wv = *(const float4*)&sWfT[c][k];
                s += av.x * wv.x + av.y * wv.y + av.z * wv.z + av.w * wv.w;
            }
            out[(size_t)n * 2 + c] = s;
        }
    }
}

// ---------------------------------------------------------------------------
extern "C" void kernel_launch(void* const* d_in, const int* in_sizes, int n_in,
                              void* d_out, int out_size, void* d_ws, size_t ws_size,
                              hipStream_t stream)
{
    (void)in_sizes; (void)n_in; (void)out_size; (void)ws_size;

    const float* x0    = (const float*)d_in[0];
    const int*   eidx  = (const int*)d_in[1];
    const float* eattr = (const float*)d_in[2];
    const float* L[3][11];
    for (int l = 0; l < 3; ++l)
        for (int j = 0; j < 11; ++j)
            L[l][j] = (const float*)d_in[4 + l * 11 + j];
    const float* mlp0W = (const float*)d_in[37];
    const float* mlp0b = (const float*)d_in[38];
    const float* mlp1W = (const float*)d_in[39];
    const float* mlp1b = (const float*)d_in[40];
    const float* finW  = (const float*)d_in[41];
    const float* finb  = (const float*)d_in[42];
    float* out = (float*)d_out;

    float* ws    = (float*)d_ws;
    float* agg   = ws;                          // N*64 (reused as v after gemm1)
    float* u     = agg  + (size_t)N_ * 64;      // N*64
    float* xbuf  = u    + (size_t)N_ * 64;      // N*64
    float* pool  = xbuf + (size_t)N_ * 64;      // G*64
    float* g0    = pool + (size_t)G_ * 64;      // G*128
    float* stats = g0   + (size_t)G_ * 128;     // 768
    float* partial = stats + 768;               // 128*NBLK
    int*   off   = (int*)(partial + 128 * NBLK); // N+1 (+1 pad)
    int*   cnt   = off + (N_ + 2);              // N
    int*   bsum  = cnt + N_;                    // 256
    int*   bpref = bsum + 256;                  // 256
    int*   rank  = bpref + 256;                 // E
    int*   src_s = rank + E_;                   // E
    unsigned short* ea_h = (unsigned short*)((((uintptr_t)(src_s + E_)) + 63) & ~(uintptr_t)63); // E*16 f16
    float* v = agg;

    const int* src = eidx;
    const int* dst = eidx + E_;
    const int GB = NBLK;

    // ---- counting sort of edges by dst (rank-based, atomic-free placement) ----
    hipMemsetAsync(cnt, 0, (size_t)N_ * sizeof(int), stream);
    hist_rank_kernel<<<2048, 256, 0, stream>>>(dst, cnt, rank);
    scanA<<<SCAN_NB, 256, 0, stream>>>(cnt, bsum);
    scanB<<<1, 256, 0, stream>>>(bsum, bpref);
    scanC<<<SCAN_NB, 256, 0, stream>>>(cnt, off, bpref);
    place_kernel<<<2048, 256, 0, stream>>>(src, dst, rank, off, eattr, src_s, ea_h);

    const int AGGB = ((N_ + DPW - 1) / DPW + 3) / 4 + 1;

    for (int l = 0; l < 3; ++l) {
        float* s1 = stats + (2 * l) * 128;
        float* s2 = stats + (2 * l + 1) * 128;
        if (l == 0) {
            agg_sorted<40><<<AGGB, 256, 0, stream>>>(ea_h, src_s, off, L[0][1], L[0][2], x0, agg);
            node_gemm<40, 0><<<GB, 256, 0, stream>>>(x0, agg, L[0][0], nullptr, nullptr, nullptr,
                                                     L[0][3], L[0][4], u, partial);
        } else {
            agg_sorted<64><<<AGGB, 256, 0, stream>>>(ea_h, src_s, off, L[l][1], L[l][2], xbuf, agg);
            node_gemm<64, 0><<<GB, 256, 0, stream>>>(xbuf, agg, L[l][0], nullptr, nullptr, nullptr,
                                                     L[l][3], L[l][4], u, partial);
        }
        finalize_stats<<<128, 256, 0, stream>>>(partial, s1);
        node_gemm<64, 1><<<GB, 256, 0, stream>>>(u, nullptr, nullptr, L[l][5], L[l][6], s1,
                                                 L[l][7], L[l][8], v, partial);
        finalize_stats<<<128, 256, 0, stream>>>(partial, s2);
        apply_bn_leaky<<<6250, 256, 0, stream>>>(v, s2, L[l][9], L[l][10], xbuf);
    }

    // ---- pool + per-graph mlp0 term + fused MLP head ----
    pool_kernel<<<G_ / 4, 256, 0, stream>>>(xbuf, pool);
    pool_mlp0<<<G_ / 2, 256, 0, stream>>>(pool, mlp0W, mlp0b, g0);
    mlp_kernel<<<(N_ + 127) / 128, 256, 0, stream>>>(xbuf, g0, mlp0W,
                                                     mlp1W, mlp1b, finW, finb, out);
}

// Round 12
// 892.236 us; speedup vs baseline: 1.5081x; 1.0147x over previous
//
#include <hip/hip_runtime.h>

// GINE-GNN forward on MI355X. Round 12:
//  - place-lite: only se[p]=(src,eid) 8B store (was 32B half-line ea scatter,
//    104MB WRITE, 107us). agg gathers edge_attr rows itself (full-line reads,
//    LLC-resident) with f16 convert in-flight, pipelined 2 chunks ahead.
//  - apply_bn_leaky fused into consumers (agg x-gather / gemm0 staging /
//    pool / mlp staging): 3 kernels + 150MB traffic deleted.

#define N_  100000
#define E_  1600000
#define G_  2000
#define SCAN_NB 196          // ceil(N / 512)
#define NBLK 1563            // ceil(N / 64)

typedef _Float16 half2v __attribute__((ext_vector_type(2)));

__device__ __forceinline__ float leaky_(float z) { return z >= 0.f ? z : 0.01f * z; }

__device__ __forceinline__ half2v u2h(unsigned u) {
    union { unsigned u; half2v h; } c; c.u = u; return c.h;
}

__device__ __forceinline__ float dot2_(half2v a, half2v b, float c) {
#if __has_builtin(__builtin_amdgcn_fdot2)
    return __builtin_amdgcn_fdot2(a, b, c, false);
#else
    return c + (float)a.x * (float)b.x + (float)a.y * (float)b.y;
#endif
}

// ---------------------------------------------------------------------------
// Counting sort of edges by dst: hist(+rank) -> scanA/B/C -> place-lite.
// ---------------------------------------------------------------------------
__global__ __launch_bounds__(256) void hist_rank_kernel(
    const int* __restrict__ dst, int* __restrict__ cnt, int* __restrict__ rank)
{
#pragma unroll 4
    for (int e = blockIdx.x * 256 + threadIdx.x; e < E_; e += gridDim.x * 256)
        rank[e] = atomicAdd(&cnt[dst[e]], 1);
}

__global__ __launch_bounds__(256) void scanA(
    const int* __restrict__ cnt, int* __restrict__ blocksum)
{
    __shared__ int s[256];
    const int t = threadIdx.x, b = blockIdx.x;
    const int i0 = (b * 256 + t) * 2;
    int v = 0;
    if (i0 < N_) v += cnt[i0];
    if (i0 + 1 < N_) v += cnt[i0 + 1];
    s[t] = v; __syncthreads();
    for (int o = 128; o > 0; o >>= 1) { if (t < o) s[t] += s[t + o]; __syncthreads(); }
    if (t == 0) blocksum[b] = s[0];
}

__global__ __launch_bounds__(256) void scanB(
    const int* __restrict__ blocksum, int* __restrict__ blockpref)
{
    __shared__ int s[256];
    const int t = threadIdx.x;
    int v = (t < SCAN_NB) ? blocksum[t] : 0;
    s[t] = v; __syncthreads();
    for (int o = 1; o < 256; o <<= 1) {
        int u = (t >= o) ? s[t - o] : 0;
        __syncthreads(); s[t] += u; __syncthreads();
    }
    blockpref[t] = s[t] - v;   // exclusive
}

__global__ __launch_bounds__(256) void scanC(
    const int* __restrict__ cnt, int* __restrict__ off,
    const int* __restrict__ blockpref)
{
    __shared__ int s[256];
    const int t = threadIdx.x, b = blockIdx.x;
    const int i0 = (b * 256 + t) * 2;
    int v0 = (i0 < N_) ? cnt[i0] : 0;
    int v1 = (i0 + 1 < N_) ? cnt[i0 + 1] : 0;
    int pv = v0 + v1;
    s[t] = pv; __syncthreads();
    for (int o = 1; o < 256; o <<= 1) {
        int u = (t >= o) ? s[t - o] : 0;
        __syncthreads(); s[t] += u; __syncthreads();
    }
    int run = blockpref[b] + s[t] - pv;
    if (i0 < N_) {
        off[i0] = run; run += v0;
        if (i0 + 1 < N_) off[i0 + 1] = run;
    }
    if (b == 0 && t == 0) off[N_] = E_;
}

// place-lite: se[off[dst]+rank] = (src, eid). One 8B store per edge.
__global__ __launch_bounds__(256) void place_kernel(
    const int* __restrict__ src, const int* __restrict__ dst,
    const int* __restrict__ rank, const int* __restrict__ off,
    int2* __restrict__ se)
{
#pragma unroll 4
    for (int e = blockIdx.x * 256 + threadIdx.x; e < E_; e += gridDim.x * 256) {
        const int p = off[dst[e]] + rank[e];
        se[p] = make_int2(src[e], e);
    }
}

// ---------------------------------------------------------------------------
// Sorted-edge aggregation: one wave owns DPW consecutive destinations.
// Staging by gather: se chunk (coalesced int2) -> shfl eid -> 2 lanes/row
// gather fp32 edge_attr row -> f16 convert -> LDS. Pipelined 2 chunks ahead.
// x gathers optionally apply BN+leaky inline (APPLY_BN).
// ---------------------------------------------------------------------------
#define DPW 13
#define CHUNK 32

template<int CI, int APPLY_BN>
__global__ __launch_bounds__(256, 4) void agg_sorted(
    const float* __restrict__ edge_attr,       // [E,16] fp32, original order
    const int2* __restrict__ se,               // [E] (src,eid) sorted by dst
    const int* __restrict__ off,
    const float* __restrict__ We, const float* __restrict__ be,
    const float* __restrict__ x,               // raw x0 or pre-BN v
    const float* __restrict__ stIn,            // APPLY_BN: sums[128]
    const float* __restrict__ bng, const float* __restrict__ bnb,
    float* __restrict__ agg)
{
    __shared__ __align__(16) unsigned s_ea[4][2][CHUNK * 8];   // 8 KB (f16 rows)
    __shared__ int s_src[4][2][CHUNK];                         // 1 KB
    const int t = threadIdx.x;
    const int lane = t & 63;
    const int w = t >> 6;
    const int wid = __builtin_amdgcn_readfirstlane(blockIdx.x * 4 + w);

    half2v wh[8];
#pragma unroll
    for (int k = 0; k < 8; ++k) wh[k] = half2v{(_Float16)0.f, (_Float16)0.f};
    float beL = 0.f, scL = 1.f, shL = 0.f;
    if (lane < CI) {
#pragma unroll
        for (int k = 0; k < 8; ++k)
            wh[k] = half2v{(_Float16)We[(2 * k) * CI + lane],
                           (_Float16)We[(2 * k + 1) * CI + lane]};
        beL = be[lane];
        if (APPLY_BN) {
            float mean = stIn[lane] * (1.0f / N_);
            float var  = stIn[64 + lane] * (1.0f / N_) - mean * mean;
            scL = bng[lane] * rsqrtf(var + 1e-5f);
            shL = bnb[lane] - mean * scL;
        }
    }
    const int ln = (lane < CI) ? lane : 0;

    const int d0 = wid * DPW;
    if (d0 >= N_) return;
    const int d1 = min(d0 + DPW, N_);
    const int pw0 = off[d0];
    const int pw1 = off[d1];
    if (pw0 >= pw1) {   // all-empty range
        for (int d = d0; d < d1; ++d)
            if (lane < CI) agg[(size_t)d * CI + lane] = 0.f;
        return;
    }

    int d = d0;
    int e1 = off[d0 + 1];
    float acc = 0.f;
    int buf = 0;
    const int r = lane >> 1;            // row this lane gathers (2 lanes/row)
    const int hf = lane & 1;            // which half of the row

    // ---- prologue: stage chunk 0 (exposed once), load se for chunk 1 ----
    {
        const int m0 = min(CHUNK, pw1 - pw0);
        int2 t0 = make_int2(0, 0);
        if (lane < m0) t0 = se[pw0 + lane];
        int e = __shfl(t0.y, r);
        if (r >= m0) e = 0;
        const float4* ep = (const float4*)(edge_attr + (size_t)e * 16 + hf * 8);
        float4 f0 = ep[0], f1 = ep[1];
        union { uint4 u; half2v h[4]; } cv;
        cv.h[0] = half2v{(_Float16)f0.x, (_Float16)f0.y};
        cv.h[1] = half2v{(_Float16)f0.z, (_Float16)f0.w};
        cv.h[2] = half2v{(_Float16)f1.x, (_Float16)f1.y};
        cv.h[3] = half2v{(_Float16)f1.z, (_Float16)f1.w};
        *(uint4*)&s_ea[w][0][r * 8 + hf * 4] = cv.u;
        if (lane < CHUNK) s_src[w][0][lane] = (lane < m0) ? t0.x : 0;
    }
    int2 pse = make_int2(0, 0);          // se for chunk n+1
    {
        const int np = pw0 + CHUNK;
        const int nm = min(CHUNK, pw1 - np);
        if (nm > 0 && lane < nm) pse = se[np + lane];
    }
    __builtin_amdgcn_wave_barrier();

    for (int cp = pw0; cp < pw1; cp += CHUNK) {
        const int m = min(CHUNK, pw1 - cp);
        const int np = cp + CHUNK;
        const int nm = min(CHUNK, pw1 - np);       // chunk n+1 size
        const int np2 = cp + 2 * CHUNK;
        const int nm2 = min(CHUNK, pw1 - np2);     // chunk n+2 size

        // (1) issue ea gather for chunk n+1 (pse resident) + se load for n+2
        float4 g0 = make_float4(0.f, 0.f, 0.f, 0.f), g1 = g0;
        if (nm > 0) {
            int ge = __shfl(pse.y, r);
            if (r >= nm) ge = 0;
            const float4* ep = (const float4*)(edge_attr + (size_t)ge * 16 + hf * 8);
            g0 = ep[0]; g1 = ep[1];
        }
        int2 nse = make_int2(0, 0);
        if (nm2 > 0 && lane < nm2) nse = se[np2 + lane];

        // (2) x gathers + compute for chunk n
        float xr[CHUNK];
#pragma unroll
        for (int i = 0; i < CHUNK; ++i) {
            const int s = s_src[w][buf][i];           // broadcast ds_read
            float raw = x[(size_t)s * CI + ln];
            xr[i] = APPLY_BN ? leaky_(raw * scL + shL) : raw;
        }
#pragma unroll
        for (int i = 0; i < CHUNK; ++i) {
            if (i >= m) break;
            while (cp + i == e1) {
                if (lane < CI) agg[(size_t)d * CI + lane] = acc;
                acc = 0.f; ++d;
                e1 = off[d + 1];
            }
            const unsigned* er = &s_ea[w][buf][i * 8];
            uint4 e0 = *(const uint4*)&er[0];          // broadcast ds_read_b128
            uint4 e2 = *(const uint4*)&er[4];
            float dotv = beL;
            dotv = dot2_(u2h(e0.x), wh[0], dotv);
            dotv = dot2_(u2h(e0.y), wh[1], dotv);
            dotv = dot2_(u2h(e0.z), wh[2], dotv);
            dotv = dot2_(u2h(e0.w), wh[3], dotv);
            dotv = dot2_(u2h(e2.x), wh[4], dotv);
            dotv = dot2_(u2h(e2.y), wh[5], dotv);
            dotv = dot2_(u2h(e2.z), wh[6], dotv);
            dotv = dot2_(u2h(e2.w), wh[7], dotv);
            float mm = xr[i] + dotv;
            acc += (mm > 0.f ? mm : 0.f);
        }

        // (3) commit chunk n+1 (convert + LDS), rotate se pipeline
        if (nm > 0) {
            union { uint4 u; half2v h[4]; } cv;
            cv.h[0] = half2v{(_Float16)g0.x, (_Float16)g0.y};
            cv.h[1] = half2v{(_Float16)g0.z, (_Float16)g0.w};
            cv.h[2] = half2v{(_Float16)g1.x, (_Float16)g1.y};
            cv.h[3] = half2v{(_Float16)g1.z, (_Float16)g1.w};
            *(uint4*)&s_ea[w][buf ^ 1][r * 8 + hf * 4] = cv.u;
            if (lane < CHUNK) s_src[w][buf ^ 1][lane] = (lane < nm) ? pse.x : 0;
        }
        pse = nse;
        __builtin_amdgcn_wave_barrier();
        buf ^= 1;
    }

    // flush current dest + trailing zero-degree dests
    while (d < d1) {
        if (lane < CI) agg[(size_t)d * CI + lane] = acc;
        acc = 0.f; ++d;
    }
}

// ---------------------------------------------------------------------------
// Node GEMM. MODE 0: stage=(1+eps)*xin+agg, xin = BNIN? leaky(BN(in)) : in.
// MODE 1: stage=leaky(BN1(u)). Per-block partial BN stats out.
// ---------------------------------------------------------------------------
template<int CI, int MODE, int BNIN>
__global__ __launch_bounds__(256, 4) void node_gemm(
    const float* __restrict__ in,
    const float* __restrict__ agg,   // MODE 0
    const float* __restrict__ eps,   // MODE 0
    const float* __restrict__ g1,    // BN params (MODE1: inner; MODE0+BNIN: prev outer)
    const float* __restrict__ bt1,
    const float* __restrict__ stIn,
    const float* __restrict__ W, const float* __restrict__ bias_,
    float* __restrict__ outbuf, float* __restrict__ partial)
{
    __shared__ __align__(16) float a_lds[64][CI + 4];
    __shared__ __align__(16) float w_lds[CI][68];
    __shared__ float s_sc[64], s_sh[64];
    const int t = threadIdx.x;
    const int n0 = blockIdx.x * 64;
    constexpr int QR = CI / 4;

    if (MODE == 1 || BNIN) {
        if (t < 64) {
            float mean = stIn[t] * (1.0f / N_);
            float var  = stIn[64 + t] * (1.0f / N_) - mean * mean;
            float sc = g1[t] * rsqrtf(var + 1e-5f);
            s_sc[t] = sc;
            s_sh[t] = bt1[t] - mean * sc;
        }
        __syncthreads();
    }

    if (MODE == 0) {
        const float hs = 1.0f + eps[0];
        for (int f = t; f < 64 * QR; f += 256) {
            int i = f / QR, q = f - i * QR;
            int n = n0 + i;
            float4 val = make_float4(0.f, 0.f, 0.f, 0.f);
            if (n < N_) {
                float4 xa = *(const float4*)&in[(size_t)n * CI + q * 4];
                float4 ag = *(const float4*)&agg[(size_t)n * CI + q * 4];
                if (BNIN) {
                    int c = q * 4;
                    xa.x = leaky_(xa.x * s_sc[c]     + s_sh[c]);
                    xa.y = leaky_(xa.y * s_sc[c + 1] + s_sh[c + 1]);
                    xa.z = leaky_(xa.z * s_sc[c + 2] + s_sh[c + 2]);
                    xa.w = leaky_(xa.w * s_sc[c + 3] + s_sh[c + 3]);
                }
                val = make_float4(hs * xa.x + ag.x, hs * xa.y + ag.y,
                                  hs * xa.z + ag.z, hs * xa.w + ag.w);
            }
            *(float4*)&a_lds[i][q * 4] = val;
        }
    } else {
        for (int f = t; f < 64 * QR; f += 256) {
            int i = f / QR, q = f - i * QR;
            int n = n0 + i;
            float4 val = make_float4(0.f, 0.f, 0.f, 0.f);
            if (n < N_) {
                float4 uv = *(const float4*)&in[(size_t)n * CI + q * 4];
                int c = q * 4;
                val = make_float4(leaky_(uv.x * s_sc[c]     + s_sh[c]),
                                  leaky_(uv.y * s_sc[c + 1] + s_sh[c + 1]),
                                  leaky_(uv.z * s_sc[c + 2] + s_sh[c + 2]),
                                  leaky_(uv.w * s_sc[c + 3] + s_sh[c + 3]));
            }
            *(float4*)&a_lds[i][q * 4] = val;
        }
    }
    for (int f = t; f < CI * 16; f += 256) {
        int k = f >> 4, cq = f & 15;
        *(float4*)&w_lds[k][cq * 4] = *(const float4*)&W[k * 64 + cq * 4];
    }
    __syncthreads();

    const int tr = t & 15;
    const int c0 = (t >> 4) * 4;
    float acc[4][4] = {};
#pragma unroll 2
    for (int k = 0; k < CI; k += 4) {
        float ar[4][4];
#pragma unroll
        for (int j = 0; j < 4; ++j)
            *(float4*)&ar[j][0] = *(const float4*)&a_lds[tr + 16 * j][k];
#pragma unroll
        for (int kk = 0; kk < 4; ++kk) {
            float4 b = *(const float4*)&w_lds[k + kk][c0];
#pragma unroll
            for (int j = 0; j < 4; ++j) {
                acc[j][0] += ar[j][kk] * b.x;
                acc[j][1] += ar[j][kk] * b.y;
                acc[j][2] += ar[j][kk] * b.z;
                acc[j][3] += ar[j][kk] * b.w;
            }
        }
    }

    const float4 bb = *(const float4*)&bias_[c0];
    const float bias[4] = { bb.x, bb.y, bb.z, bb.w };
    float ls[4] = {}, lq[4] = {};
#pragma unroll
    for (int j = 0; j < 4; ++j) {
        int n = n0 + tr + 16 * j;
        if (n < N_) {
            float o[4];
#pragma unroll
            for (int cc = 0; cc < 4; ++cc) {
                o[cc] = acc[j][cc] + bias[cc];
                ls[cc] += o[cc];
                lq[cc] += o[cc] * o[cc];
            }
            *(float4*)&outbuf[(size_t)n * 64 + c0] = make_float4(o[0], o[1], o[2], o[3]);
        }
    }
#pragma unroll
    for (int m = 1; m <= 8; m <<= 1) {
#pragma unroll
        for (int cc = 0; cc < 4; ++cc) {
            ls[cc] += __shfl_xor(ls[cc], m);
            lq[cc] += __shfl_xor(lq[cc], m);
        }
    }
    if (tr == 0) {
#pragma unroll
        for (int cc = 0; cc < 4; ++cc) {
            partial[(size_t)(c0 + cc) * NBLK + blockIdx.x]      = ls[cc];
            partial[(size_t)(64 + c0 + cc) * NBLK + blockIdx.x] = lq[cc];
        }
    }
}

__global__ __launch_bounds__(256) void finalize_stats(
    const float* __restrict__ partial, float* __restrict__ stats)
{
    const int c = blockIdx.x;
    const int t = threadIdx.x;
    float s = 0.f;
    for (int b = t; b < NBLK; b += 256) s += partial[(size_t)c * NBLK + b];
    __shared__ float red[256];
    red[t] = s; __syncthreads();
    for (int o = 128; o > 0; o >>= 1) { if (t < o) red[t] += red[t + o]; __syncthreads(); }
    if (t == 0) stats[c] = red[0];
}

// ---------------------------------------------------------------------------
// Pool with fused BN+leaky: pool[g] = sum_j leaky(BN(v[g*50+j])).
// ---------------------------------------------------------------------------
__global__ __launch_bounds__(256) void pool_kernel(
    const float* __restrict__ v, const float* __restrict__ st,
    const float* __restrict__ bg, const float* __restrict__ bb,
    float* __restrict__ pool)
{
    const int c = threadIdx.x & 63;
    const int g = blockIdx.x * 4 + (threadIdx.x >> 6);
    float mean = st[c] * (1.0f / N_);
    float var  = st[64 + c] * (1.0f / N_) - mean * mean;
    float sc = bg[c] * rsqrtf(var + 1e-5f);
    float sh = bb[c] - mean * sc;
    const float* p = v + (size_t)g * 50 * 64 + c;
    float s = 0.f;
#pragma unroll
    for (int j = 0; j < 50; ++j) s += leaky_(p[(size_t)j * 64] * sc + sh);
    pool[(size_t)g * 64 + c] = s;
}

// g0[g][c] = pool[g] @ W0b + b0  (W0b = W0 rows 64..127). 2 graphs/block.
__global__ __launch_bounds__(256) void pool_mlp0(
    const float* __restrict__ pool, const float* __restrict__ W0,
    const float* __restrict__ b0, float* __restrict__ g0)
{
    const int t = threadIdx.x;
    const int g = blockIdx.x * 2 + (t >> 7);
    const int c = t & 127;
    float s = b0[c];
    const float* pr = pool + (size_t)g * 64;
#pragma unroll 4
    for (int k = 0; k < 64; ++k)
        s += pr[k] * W0[(size_t)(64 + k) * 128 + c];
    g0[(size_t)g * 128 + c] = s;
}

// ---------------------------------------------------------------------------
// Fused MLP head, BN+leaky applied when staging v.
// ---------------------------------------------------------------------------
__global__ __launch_bounds__(256, 2) void mlp_kernel(
    const float* __restrict__ v, const float* __restrict__ st,
    const float* __restrict__ bg, const float* __restrict__ bb,
    const float* __restrict__ g0,
    const float* __restrict__ W0,
    const float* __restrict__ W1, const float* __restrict__ b1,
    const float* __restrict__ Wf, const float* __restrict__ bf,
    float* __restrict__ out)
{
    __shared__ __align__(16) float a_lds[128][132];   // 67.6 KB
    __shared__ __align__(16) float w_lds[16][132];    // 8.4 KB
    __shared__ __align__(16) float sWfT[2][128];
    __shared__ float s_scm[64], s_shm[64];
    __shared__ int sbid[128];
    const int t = threadIdx.x;
    const int n0 = blockIdx.x * 128;

    if (t < 64) {
        float mean = st[t] * (1.0f / N_);
        float var  = st[64 + t] * (1.0f / N_) - mean * mean;
        float sc = bg[t] * rsqrtf(var + 1e-5f);
        s_scm[t] = sc;
        s_shm[t] = bb[t] - mean * sc;
    }
    __syncthreads();

    for (int f = t; f < 128 * 16; f += 256) {
        int i = f >> 4, q = f & 15;
        int n = n0 + i;
        float4 val = make_float4(0.f, 0.f, 0.f, 0.f);
        if (n < N_) {
            float4 xv = *(const float4*)&v[(size_t)n * 64 + q * 4];
            int c = q * 4;
            val = make_float4(leaky_(xv.x * s_scm[c]     + s_shm[c]),
                              leaky_(xv.y * s_scm[c + 1] + s_shm[c + 1]),
                              leaky_(xv.z * s_scm[c + 2] + s_shm[c + 2]),
                              leaky_(xv.w * s_scm[c + 3] + s_shm[c + 3]));
        }
        *(float4*)&a_lds[i][q * 4] = val;
    }
    if (t < 128) {
        int n = n0 + t;
        sbid[t] = (n < N_) ? (n / 50) : (G_ - 1);
        sWfT[0][t] = Wf[t * 2];
        sWfT[1][t] = Wf[t * 2 + 1];
    }

    const int tr = t & 15;
    const int c0 = (t >> 4) * 8;
    float acc[8][8];

#pragma unroll
    for (int j = 0; j < 8; ++j)
#pragma unroll
        for (int cc = 0; cc < 8; ++cc) acc[j][cc] = 0.f;

    for (int kc = 0; kc < 64; kc += 16) {
        __syncthreads();
        for (int f = t; f < 16 * 32; f += 256) {
            int k = f >> 5, cq = f & 31;
            *(float4*)&w_lds[k][cq * 4] = *(const float4*)&W0[(size_t)(kc + k) * 128 + cq * 4];
        }
        __syncthreads();
        for (int k = 0; k < 16; k += 4) {
            float ar[8][4];
#pragma unroll
            for (int j = 0; j < 8; ++j)
                *(float4*)&ar[j][0] = *(const float4*)&a_lds[tr + 16 * j][kc + k];
#pragma unroll
            for (int kk = 0; kk < 4; ++kk) {
                float4 bA = *(const float4*)&w_lds[k + kk][c0];
                float4 bB = *(const float4*)&w_lds[k + kk][c0 + 4];
#pragma unroll
                for (int j = 0; j < 8; ++j) {
                    acc[j][0] += ar[j][kk] * bA.x;
                    acc[j][1] += ar[j][kk] * bA.y;
                    acc[j][2] += ar[j][kk] * bA.z;
                    acc[j][3] += ar[j][kk] * bA.w;
                    acc[j][4] += ar[j][kk] * bB.x;
                    acc[j][5] += ar[j][kk] * bB.y;
                    acc[j][6] += ar[j][kk] * bB.z;
                    acc[j][7] += ar[j][kk] * bB.w;
                }
            }
        }
    }
    __syncthreads();
#pragma unroll
    for (int j = 0; j < 8; ++j) {
        int row = tr + 16 * j;
        const float* gr = g0 + (size_t)sbid[row] * 128;
        float4 gA = *(const float4*)&gr[c0];
        float4 gB = *(const float4*)&gr[c0 + 4];
        float o[8] = { acc[j][0] + gA.x, acc[j][1] + gA.y, acc[j][2] + gA.z, acc[j][3] + gA.w,
                       acc[j][4] + gB.x, acc[j][5] + gB.y, acc[j][6] + gB.z, acc[j][7] + gB.w };
#pragma unroll
        for (int cc = 0; cc < 8; ++cc) o[cc] = leaky_(o[cc]);
        *(float4*)&a_lds[row][c0]     = make_float4(o[0], o[1], o[2], o[3]);
        *(float4*)&a_lds[row][c0 + 4] = make_float4(o[4], o[5], o[6], o[7]);
    }

#pragma unroll
    for (int j = 0; j < 8; ++j)
#pragma unroll
        for (int cc = 0; cc < 8; ++cc) acc[j][cc] = 0.f;

    for (int kc = 0; kc < 128; kc += 16) {
        __syncthreads();
        for (int f = t; f < 16 * 32; f += 256) {
            int k = f >> 5, cq = f & 31;
            *(float4*)&w_lds[k][cq * 4] = *(const float4*)&W1[(size_t)(kc + k) * 128 + cq * 4];
        }
        __syncthreads();
        for (int k = 0; k < 16; k += 4) {
            float ar[8][4];
#pragma unroll
            for (int j = 0; j < 8; ++j)
                *(float4*)&ar[j][0] = *(const float4*)&a_lds[tr + 16 * j][kc + k];
#pragma unroll
            for (int kk = 0; kk < 4; ++kk) {
                float4 bA = *(const float4*)&w_lds[k + kk][c0];
                float4 bB = *(const float4*)&w_lds[k + kk][c0 + 4];
#pragma unroll
                for (int j = 0; j < 8; ++j) {
                    acc[j][0] += ar[j][kk] * bA.x;
                    acc[j][1] += ar[j][kk] * bA.y;
                    acc[j][2] += ar[j][kk] * bA.z;
                    acc[j][3] += ar[j][kk] * bA.w;
                    acc[j][4] += ar[j][kk] * bB.x;
                    acc[j][5] += ar[j][kk] * bB.y;
                    acc[j][6] += ar[j][kk] * bB.z;
                    acc[j][7] += ar[j][kk] * bB.w;
                }
            }
        }
    }
    __syncthreads();
    {
        float4 bb0 = *(const float4*)&b1[c0];
        float4 bb1 = *(const float4*)&b1[c0 + 4];
        float bias[8] = { bb0.x, bb0.y, bb0.z, bb0.w, bb1.x, bb1.y, bb1.z, bb1.w };
#pragma unroll
        for (int j = 0; j < 8; ++j) {
            int row = tr + 16 * j;
            float o[8];
#pragma unroll
            for (int cc = 0; cc < 8; ++cc) o[cc] = leaky_(acc[j][cc] + bias[cc]);
            *(float4*)&a_lds[row][c0]     = make_float4(o[0], o[1], o[2], o[3]);
            *(float4*)&a_lds[row][c0 + 4] = make_float4(o[4], o[5], o[6], o[7]);
        }
    }
    __syncthreads();

    {
        int i = t >> 1, c = t & 1;
        int n = n0 + i;
        if (n < N_) {
            float s = bf[c];
            for (int k = 0; k < 128; k += 4) {
                float4 av = *(const float4*)&a_lds[i][k];
                float4 wv = *(const float4*)&sWfT[c][k];
                s += av.x * wv.x + av.y * wv.y + av.z * wv.z + av.w * wv.w;
            }
            out[(size_t)n * 2 + c] = s;
        }
    }
}

// ---------------------------------------------------------------------------
extern "C" void kernel_launch(void* const* d_in, const int* in_sizes, int n_in,
                              void* d_out, int out_size, void* d_ws, size_t ws_size,
                              hipStream_t stream)
{
    (void)in_sizes; (void)n_in; (void)out_size; (void)ws_size;

    const float* x0    = (const float*)d_in[0];
    const int*   eidx  = (const int*)d_in[1];
    const float* eattr = (const float*)d_in[2];
    const float* L[3][11];
    for (int l = 0; l < 3; ++l)
        for (int j = 0; j < 11; ++j)
            L[l][j] = (const float*)d_in[4 + l * 11 + j];
    const float* mlp0W = (const float*)d_in[37];
    const float* mlp0b = (const float*)d_in[38];
    const float* mlp1W = (const float*)d_in[39];
    const float* mlp1b = (const float*)d_in[40];
    const float* finW  = (const float*)d_in[41];
    const float* finb  = (const float*)d_in[42];
    float* out = (float*)d_out;

    float* ws    = (float*)d_ws;
    float* P0    = ws;                          // N*64 (agg)
    float* P1    = P0 + (size_t)N_ * 64;        // N*64 (u)
    float* P2    = P1 + (size_t)N_ * 64;        // N*64 (v, pre-BN)
    float* pool  = P2 + (size_t)N_ * 64;        // G*64
    float* g0    = pool + (size_t)G_ * 64;      // G*128
    float* stats = g0   + (size_t)G_ * 128;     // 768
    float* partial = stats + 768;               // 128*NBLK
    int*   off   = (int*)(partial + 128 * NBLK); // N+1 (+1 pad)
    int*   cnt   = off + (N_ + 2);              // N
    int*   bsum  = cnt + N_;                    // 256
    int*   bpref = bsum + 256;                  // 256
    int*   rank  = bpref + 256;                 // E
    int2*  se    = (int2*)(rank + E_);          // E (8B aligned)

    const int* src = eidx;
    const int* dst = eidx + E_;
    const int GB = NBLK;

    // ---- counting sort of edges by dst (rank-based, atomic-free placement) ----
    hipMemsetAsync(cnt, 0, (size_t)N_ * sizeof(int), stream);
    hist_rank_kernel<<<2048, 256, 0, stream>>>(dst, cnt, rank);
    scanA<<<SCAN_NB, 256, 0, stream>>>(cnt, bsum);
    scanB<<<1, 256, 0, stream>>>(bsum, bpref);
    scanC<<<SCAN_NB, 256, 0, stream>>>(cnt, off, bpref);
    place_kernel<<<2048, 256, 0, stream>>>(src, dst, rank, off, se);

    const int AGGB = ((N_ + DPW - 1) / DPW + 3) / 4 + 1;

    for (int l = 0; l < 3; ++l) {
        float* s1 = stats + (2 * l) * 128;
        float* s2 = stats + (2 * l + 1) * 128;
        if (l == 0) {
            agg_sorted<40, 0><<<AGGB, 256, 0, stream>>>(eattr, se, off, L[0][1], L[0][2],
                                                        x0, nullptr, nullptr, nullptr, P0);
            node_gemm<40, 0, 0><<<GB, 256, 0, stream>>>(x0, P0, L[0][0], nullptr, nullptr, nullptr,
                                                        L[0][3], L[0][4], P1, partial);
        } else {
            float* sp = stats + (2 * l - 1) * 128;   // prev layer outer stats
            agg_sorted<64, 1><<<AGGB, 256, 0, stream>>>(eattr, se, off, L[l][1], L[l][2],
                                                        P2, sp, L[l - 1][9], L[l - 1][10], P0);
            node_gemm<64, 0, 1><<<GB, 256, 0, stream>>>(P2, P0, L[l][0], L[l - 1][9], L[l - 1][10], sp,
                                                        L[l][3], L[l][4], P1, partial);
        }
        finalize_stats<<<128, 256, 0, stream>>>(partial, s1);
        node_gemm<64, 1, 0><<<GB, 256, 0, stream>>>(P1, nullptr, nullptr, L[l][5], L[l][6], s1,
                                                    L[l][7], L[l][8], P2, partial);
        finalize_stats<<<128, 256, 0, stream>>>(partial, s2);
    }

    // ---- pool + per-graph mlp0 term + fused MLP head (BN applied inline) ----
    float* sF = stats + 5 * 128;
    pool_kernel<<<G_ / 4, 256, 0, stream>>>(P2, sF, L[2][9], L[2][10], pool);
    pool_mlp0<<<G_ / 2, 256, 0, stream>>>(pool, mlp0W, mlp0b, g0);
    mlp_kernel<<<(N_ + 127) / 128, 256, 0, stream>>>(P2, sF, L[2][9], L[2][10], g0, mlp0W,
                                                     mlp1W, mlp1b, finW, finb, out);
}